// Round 17
// baseline (434.619 us; speedup 1.0000x reference)
//
#include <hip/hip_runtime.h>
#include <hip/hip_bf16.h>
#include <math.h>

#define NTRK 256
#define DLAT 128
#define CDIM 7
#define CD2  49
#define CD4  2401
#define NH1  384
#define NH2  256
#define LDK  2432    // CD4 padded to multiple of 32
#define PITCHB 272   // corr LDS row pitch in bytes (136 bf16 / 68 dwords) -> 4-bank skew

// channel-last level sizes (elements)
#define SZ_L0 ((size_t)3 * 8 * 96 * 96 * 128)
#define SZ_L1 ((size_t)3 * 8 * 48 * 48 * 128)
#define SZ_L2 ((size_t)3 * 8 * 24 * 24 * 128)
#define SZ_L3 ((size_t)3 * 8 * 12 * 12 * 128)
#define SZ_TF ((size_t)3 * NTRK * DLAT * CD2)

typedef __attribute__((ext_vector_type(8))) short short8;
typedef __attribute__((ext_vector_type(4))) float f32x4;
typedef __attribute__((ext_vector_type(4))) unsigned int u32x4;

// ---------------- helpers ----------------

__device__ __forceinline__ float b2f(unsigned short u) {
    union { unsigned int i; float f; } c;
    c.i = ((unsigned int)u) << 16;
    return c.f;
}
__device__ __forceinline__ unsigned int f2b(float x) {
    __hip_bfloat16 h = __float2bfloat16(x);
    return (unsigned int)(*(unsigned short*)&h);
}

// 0.5x(1+tanh(u)) == x*sigmoid(2u), u = 0.7978845608(x + 0.044715 x^3)
__device__ __forceinline__ float gelu_tanh(float x) {
    float x2 = x * x;
    float p = x * fmaf(0.044715f, x2, 1.0f);
    float e = __expf(-1.5957691216f * p);   // e^{-2u}
    return __fdividef(x, 1.0f + e);
}

__device__ __forceinline__ int plane_a(int k) { return (k == 2) ? 1 : 0; }
__device__ __forceinline__ int plane_b(int k) { return (k == 0) ? 1 : 2; }

__device__ __forceinline__ int lev_v(int lev) { return 96 >> lev; }
__device__ __forceinline__ size_t lev_off(int lev) {
    return (lev > 0 ? SZ_L0 : 0) + (lev > 1 ? SZ_L1 : 0) + (lev > 2 ? SZ_L2 : 0);
}

// async global->LDS, 16B per lane; LDS dst must be wave-uniform base
__device__ __forceinline__ void gload16(const void* g, void* l) {
    __builtin_amdgcn_global_load_lds(
        (const __attribute__((address_space(1))) unsigned int*)g,
        (__attribute__((address_space(3))) unsigned int*)l,
        16, 0, 0);
}

// ---------------- fp32 channel-first -> bf16 channel-last transpose ----------------

__global__ __launch_bounds__(256) void cvt_cl_kernel(const float* __restrict__ in,
                                                     __hip_bfloat16* __restrict__ out) {
    __shared__ unsigned int lds[64][97];   // lds[d2][x] = bf16(2*d2) | bf16(2*d2+1)<<16
    const int b = blockIdx.x;      // (k*8+s)*96 + y
    const int y = b % 96;
    const int ks = b / 96;         // k*8+s
    const int k = ks >> 3, s = ks & 7;
    const int tid = threadIdx.x;
    for (int idx = tid; idx < 64 * 24; idx += 256) {
        int d2 = idx / 24, x4 = (idx - d2 * 24) * 4;
        const float* rlo = in + (((size_t)s * 384 + (2 * d2) * 3 + k) * 96 + y) * 96 + x4;
        const float* rhi = in + (((size_t)s * 384 + (2 * d2 + 1) * 3 + k) * 96 + y) * 96 + x4;
        float4 lo = *(const float4*)rlo;
        float4 hi = *(const float4*)rhi;
        lds[d2][x4 + 0] = f2b(lo.x) | (f2b(hi.x) << 16);
        lds[d2][x4 + 1] = f2b(lo.y) | (f2b(hi.y) << 16);
        lds[d2][x4 + 2] = f2b(lo.z) | (f2b(hi.z) << 16);
        lds[d2][x4 + 3] = f2b(lo.w) | (f2b(hi.w) << 16);
    }
    __syncthreads();
    unsigned int* orow = (unsigned int*)((unsigned short*)out + ((size_t)ks * 96 + y) * 96 * 128);
    for (int idx = tid; idx < 96 * 16; idx += 256) {
        int x = idx >> 4, q = idx & 15;
        u32x4 r;
        r[0] = lds[4 * q + 0][x];
        r[1] = lds[4 * q + 1][x];
        r[2] = lds[4 * q + 2][x];
        r[3] = lds[4 * q + 3][x];
        *(u32x4*)(orow + x * 64 + q * 4) = r;
    }
}

// ---------------- 2x2 avg pool, channel-last bf16 ----------------

__global__ __launch_bounds__(256) void pool_cl(const __hip_bfloat16* __restrict__ in,
                                               __hip_bfloat16* __restrict__ out,
                                               int vin, int total8) {
    int idx = blockIdx.x * 256 + threadIdx.x;
    if (idx >= total8) return;
    int vout = vin >> 1;
    int d8 = idx & 15;
    int t = idx >> 4;
    int x = t % vout; t /= vout;
    int y = t % vout; t /= vout;   // t = ks
    const unsigned short* base = (const unsigned short*)in
        + (((size_t)t * vin + 2 * y) * vin + 2 * x) * 128 + d8 * 8;
    short8 a = *(const short8*)(base);
    short8 bq = *(const short8*)(base + 128);
    short8 c = *(const short8*)(base + (size_t)vin * 128);
    short8 d = *(const short8*)(base + (size_t)vin * 128 + 128);
    short8 r;
    #pragma unroll
    for (int j = 0; j < 8; ++j) {
        float sum = b2f((unsigned short)a[j]) + b2f((unsigned short)bq[j])
                  + b2f((unsigned short)c[j]) + b2f((unsigned short)d[j]);
        r[j] = (short)f2b(0.25f * sum);
    }
    *(short8*)((unsigned short*)out + ((((size_t)t * vout + y) * vout + x)) * 128 + d8 * 8) = r;
}

// ---------------- track features, all levels: grid 4*768 ----------------

__global__ __launch_bounds__(256) void tf_all(const __hip_bfloat16* __restrict__ levbase,
                                              const float* __restrict__ coords_init,
                                              __hip_bfloat16* __restrict__ tfb) {
    const int bid = blockIdx.x;
    const int lev = bid / 768;
    const int r0 = bid - lev * 768;
    const int g = (r0 & 7) * 96 + (r0 >> 3);
    const int k = g >> 8;
    const int n = g & 255;
    const int v = lev_v(lev);
    const float inv_scale = 1.f / (float)(1 << lev);
    const float vm1 = (float)(v - 1);
    float cx = coords_init[n * 3 + plane_a(k)] * inv_scale;
    float cy = coords_init[n * 3 + plane_b(k)] * inv_scale;
    const unsigned short* frame = (const unsigned short*)levbase + lev_off(lev)
        + (size_t)(k * 8) * v * v * 128;
    unsigned short* dst = (unsigned short*)tfb + (size_t)lev * SZ_TF
        + ((size_t)(k * NTRK + n)) * (DLAT * CD2);
    for (int idx = threadIdx.x; idx < CD2 * 16; idx += 256) {
        int xy = idx >> 4;
        int c8 = idx & 15;
        int i = xy / CDIM, j = xy % CDIM;
        float X = fminf(fmaxf(cx + (float)(i - 3), 0.f), vm1);
        float Y = fminf(fmaxf(cy + (float)(j - 3), 0.f), vm1);
        float xf = floorf(X), yf = floorf(Y);
        int x0 = (int)xf, y0 = (int)yf;
        int x1 = min(x0 + 1, v - 1), y1 = min(y0 + 1, v - 1);
        float wx = X - xf, wy = Y - yf;
        const unsigned short* r00 = frame + ((size_t)y0 * v + x0) * 128 + c8 * 8;
        const unsigned short* r01 = frame + ((size_t)y0 * v + x1) * 128 + c8 * 8;
        const unsigned short* r10 = frame + ((size_t)y1 * v + x0) * 128 + c8 * 8;
        const unsigned short* r11 = frame + ((size_t)y1 * v + x1) * 128 + c8 * 8;
        short8 a = *(const short8*)r00, bq = *(const short8*)r01;
        short8 c = *(const short8*)r10, d = *(const short8*)r11;
        float w00 = (1.f - wy) * (1.f - wx), w01 = (1.f - wy) * wx;
        float w10 = wy * (1.f - wx), w11 = wy * wx;
        short8 r;
        #pragma unroll
        for (int e = 0; e < 8; ++e) {
            float val = b2f((unsigned short)a[e]) * w00 + b2f((unsigned short)bq[e]) * w01
                      + b2f((unsigned short)c[e]) * w10 + b2f((unsigned short)d[e]) * w11;
            r[e] = (short)f2b(val);
        }
        *(short8*)(dst + xy * 128 + c8 * 8) = r;
    }
}

// ---------------- fused patch-MFMA correlation v3: grid 3072 ----------------
// bid = lk*256 + n, lk = lev*3 + k.
// Prologue: stage tf into cbuf, read the 16 s-invariant bf fragments into REGISTERS
// (64 VGPRs) -- MFMA-phase LDS reads drop 20 -> 4 per lane per s. cbuf is then
// reused as the Cfull buffer, enabling the 2-barrier pipeline WITHOUT extra LDS
// (r12's schedule; its regression was the LDS-occupancy loss, avoided here):
//  X: commit patch(s) | weights(s)->wxs[s&1] | interp(s-1) from cbuf
//  Y: MFMA(s) (af from patch, bf regs) | PREF(s+1) | Cfull(s)->cbuf
// Hazards: barA orders interp(s-1) before Cfull(s) and commit before af reads;
// barB orders af reads before commit(s+1) and Cfull before interp(s).
// LDS 35.3 KB -> 4 blocks/CU; __launch_bounds__(256,4) caps VGPR at 128.
// Patch axis convention (verified r6): output (h,w) samples X=cx+(h-3), Y=cy+(w-3);
// patch pos = py*8+px (px<->x); tap for (h,w) is pos = w*8+h; wx=wxs[h], wy=wys[w].

__global__ __launch_bounds__(256, 4) void corr_all(const __hip_bfloat16* __restrict__ levbase,
                                                   const float* __restrict__ coords,
                                                   const __hip_bfloat16* __restrict__ tfb,
                                                   __hip_bfloat16* __restrict__ c4b) {
    __shared__ __align__(16) char patch[64 * PITCHB];  // P bf16 [pos][dd]
    __shared__ __align__(16) char cbuf[64 * PITCHB];   // tf staging, then Cfull fp32 [pos][xy]
    __shared__ float wxs[2][8], wys[2][8];
    const int bid = blockIdx.x;
    const int lk = bid >> 8;          // lev*3 + k
    const int n = bid & 255;
    const int lev = lk / 3;
    const int k = lk - lev * 3;
    const int v = lev_v(lev);
    const int vv = v * v;
    const float inv_scale = 1.f / (float)(1 << lev);
    const int tid = threadIdx.x;
    const float vm1 = (float)(v - 1);

    const int w4 = tid >> 6, l = tid & 63;
    const int l15 = l & 15, l4 = l >> 4;

    // stage tf into cbuf (one-time)
    const short8* tfg = (const short8*)(tfb + (size_t)lev * SZ_TF
        + ((size_t)(k * NTRK + n)) * (DLAT * CD2));
    for (int idx = tid; idx < 784; idx += 256) {
        int row = idx >> 4, c16 = idx & 15;
        *(short8*)(cbuf + row * PITCHB + c16 * 16) = tfg[idx];
    }
    __syncthreads();

    // s-invariant tf fragments -> registers (16 x short8)
    short8 bfr[4][4];
    #pragma unroll
    for (int nt = 0; nt < 4; ++nt)
        #pragma unroll
        for (int ks = 0; ks < 4; ++ks)
            bfr[nt][ks] = *(const short8*)(cbuf + (16 * nt + l15) * PITCHB + ks * 64 + l4 * 16);

    // per-thread interp decode: hw = hwb + 5*it, xy fixed
    const int hwb = tid / 49;           // 0..5 (valid <245)
    const int xy  = tid - hwb * 49;
    const bool act = tid < 245;

    const unsigned short* fbase = (const unsigned short*)levbase + lev_off(lev)
        + (size_t)(k * 8) * vv * 128;

    // per-lane staging geometry: pos = posb + 16q, fixed c8
    const int c8 = tid & 15;
    const int posb = tid >> 4;

    float cxc, cyc; int fxc, fyc;
    short8 pre[4];

    auto CALC = [&](int s) {
        const int sn = s * 256 + n;
        cxc = coords[sn * 3 + plane_a(k)] * inv_scale;
        cyc = coords[sn * 3 + plane_b(k)] * inv_scale;
        fxc = (int)floorf(cxc);
        fyc = (int)floorf(cyc);
    };
    auto PREF = [&](int s) {
        const unsigned short* frame = fbase + (size_t)s * vv * 128;
        #pragma unroll
        for (int q = 0; q < 4; ++q) {
            int pos = posb + 16 * q;
            int px = pos & 7, py = pos >> 3;
            int gx = min(max(fxc + px - 3, 0), v - 1);
            int gy = min(max(fyc + py - 3, 0), v - 1);
            pre[q] = *(const short8*)(frame + ((size_t)gy * v + gx) * 128 + c8 * 8);
        }
    };
    auto INTERP = [&](int sp) {
        unsigned short* crow = (unsigned short*)c4b + ((size_t)lk * 2048 + sp * 256 + n) * LDK;
        const int p = sp & 1;
        if (act) {
            int h = 0, w = hwb;
            unsigned short* op = crow + tid;   // hwb*49 + xy == tid
            const char* colbase = cbuf + xy * 4;
            #pragma unroll
            for (int it = 0; it < 10; ++it) {
                if (h < 7) {
                    float wxv = wxs[p][h], wyv = wys[p][w];
                    const char* tap = colbase + (w * 8 + h) * PITCHB;
                    float p00 = *(const float*)(tap);
                    float p01 = *(const float*)(tap + PITCHB);        // x+1
                    float p10 = *(const float*)(tap + 8 * PITCHB);    // y+1
                    float p11 = *(const float*)(tap + 9 * PITCHB);
                    float a  = fmaf(wxv, p01 - p00, p00);
                    float bq = fmaf(wxv, p11 - p10, p10);
                    *op = (unsigned short)f2b(fmaf(wyv, bq - a, a));
                }
                w += 5; if (w >= 7) { w -= 7; h += 1; }
                op += 245;
            }
        }
        if (tid < LDK - CD4) crow[CD4 + tid] = 0;   // bf16 zero pad
    };

    CALC(0); PREF(0);
    for (int s = 0; s < 8; ++s) {
        // ---- phase X: commit patch(s), weights(s), interp(s-1) ----
        #pragma unroll
        for (int q = 0; q < 4; ++q)
            *(short8*)(patch + (posb + 16 * q) * PITCHB + c8 * 16) = pre[q];
        if (tid < 7) {
            float X = fminf(fmaxf(cxc + (float)(tid - 3), 0.f), vm1);
            int g = min(max(fxc + tid - 3, 0), v - 1);
            wxs[s & 1][tid] = X - (float)g;
            float Y = fminf(fmaxf(cyc + (float)(tid - 3), 0.f), vm1);
            int gy_ = min(max(fyc + tid - 3, 0), v - 1);
            wys[s & 1][tid] = Y - (float)gy_;
        }
        if (s > 0) INTERP(s - 1);
        __syncthreads();   // barrier A

        // ---- phase Y: MFMA(s) (bf from regs), PREF(s+1), Cfull -> cbuf ----
        f32x4 acc[4];
        #pragma unroll
        for (int nt = 0; nt < 4; ++nt) acc[nt] = (f32x4){0.f, 0.f, 0.f, 0.f};
        #pragma unroll
        for (int ks = 0; ks < 4; ++ks) {
            short8 af = *(const short8*)(patch + (16 * w4 + l15) * PITCHB + ks * 64 + l4 * 16);
            #pragma unroll
            for (int nt = 0; nt < 4; ++nt)
                acc[nt] = __builtin_amdgcn_mfma_f32_16x16x32_bf16(af, bfr[nt][ks], acc[nt], 0, 0, 0);
        }
        if (s < 7) { CALC(s + 1); PREF(s + 1); }
        {
            const int row0 = 16 * w4 + l4 * 4;
            #pragma unroll
            for (int nt = 0; nt < 4; ++nt) {
                int col = nt * 16 + l15;
                #pragma unroll
                for (int j = 0; j < 4; ++j)
                    *(float*)(cbuf + (row0 + j) * PITCHB + col * 4) = acc[nt][j];
            }
        }
        __syncthreads();   // barrier B
    }
    INTERP(7);
}

// ---------------- weight prep: coalesced LDS-tile transpose + bf16 ----------------

__global__ __launch_bounds__(256) void prep_w1t(const float* __restrict__ w1,
                                                __hip_bfloat16* __restrict__ w1t) {
    __shared__ float t[64][65];
    const int kk0 = blockIdx.x * 64, n0 = blockIdx.y * 64;
    const int tid = threadIdx.x;
    for (int idx = tid; idx < 4096; idx += 256) {
        int r = idx >> 6, c = idx & 63;        // r: kk offset, c: n offset
        int kk = kk0 + r;
        t[r][c] = (kk < CD4) ? w1[(size_t)kk * NH1 + n0 + c] : 0.f;
    }
    __syncthreads();
    for (int idx = tid; idx < 4096; idx += 256) {
        int r = idx >> 6, c = idx & 63;        // r: n offset, c: kk offset
        w1t[(size_t)(n0 + r) * LDK + kk0 + c] = __float2bfloat16(t[c][r]);
    }
}

__global__ __launch_bounds__(256) void prep_w2t(const float* __restrict__ w2,
                                                __hip_bfloat16* __restrict__ w2t) {
    int idx = blockIdx.x * 256 + threadIdx.x;  // n*NH1 + j
    if (idx >= NH2 * NH1) return;
    int n = idx / NH1, j = idx - n * NH1;
    w2t[idx] = __float2bfloat16(w2[(size_t)j * NH2 + n]);
}

// ---------------- GEMM1 MFMA, all levels: (24576 x LDK) @ w1t^T -> gelu -> H bf16 ----------------
// BM=128 BN=128 BK=32, 4 waves (2x2), wave tile 64x64 = 4x4 frags.
// 1D grid 576; XCD-aware decode: g=id/24, m=g*8+id%8, y=(id%24)/8.
// id%8 == m%8 -> all 3 y-blocks of an m-tile land on the SAME XCD 8 slots apart:
// the 623KB A-tile is fetched once and L2-hit twice.

__global__ __launch_bounds__(256) void gemm1_all(
    const __hip_bfloat16* __restrict__ A,    // [24576][LDK]
    const __hip_bfloat16* __restrict__ Bt,   // [NH1][LDK]
    const float* __restrict__ b1,
    __hip_bfloat16* __restrict__ H) {        // [24576][NH1]
    __shared__ __align__(16) char smem[16384];
    char* Asm = smem;          // 128 rows x 64B
    char* Bsm = smem + 8192;   // 128 rows x 64B
    const int id = blockIdx.x;
    const int gq = id / 24, rq = id - gq * 24;
    const int m0 = (gq * 8 + (rq & 7)) * 128;
    const int n0 = (rq >> 3) * 128;
    const int tid = threadIdx.x;
    const int w = tid >> 6, l = tid & 63;
    const int wr = w >> 1, wc = w & 1;
    const int l15 = l & 15, l4 = l >> 4;
    f32x4 acc[4][4];
    #pragma unroll
    for (int m = 0; m < 4; ++m)
        #pragma unroll
        for (int n = 0; n < 4; ++n) acc[m][n] = (f32x4){0.f, 0.f, 0.f, 0.f};
    const char* Ag = (const char*)(A + (size_t)(m0 + (tid >> 2)) * LDK) + (tid & 3) * 16;
    const char* Bg = (const char*)(Bt + (size_t)(n0 + (tid >> 2)) * LDK) + (tid & 3) * 16;
    char* AsmW = Asm + w * 1024;
    char* BsmW = Bsm + w * 1024;
    for (int kb = 0; kb < LDK * 2; kb += 64) {  // byte offset along K
        gload16(Ag + kb, AsmW);
        gload16(Ag + (size_t)64 * LDK * 2 + kb, AsmW + 4096);
        gload16(Bg + kb, BsmW);
        gload16(Bg + (size_t)64 * LDK * 2 + kb, BsmW + 4096);
        __syncthreads();
        short8 af[4], bfr[4];
        #pragma unroll
        for (int m = 0; m < 4; ++m)
            af[m] = *(const short8*)(Asm + (wr * 64 + m * 16 + l15) * 64 + l4 * 16);
        #pragma unroll
        for (int n = 0; n < 4; ++n)
            bfr[n] = *(const short8*)(Bsm + (wc * 64 + n * 16 + l15) * 64 + l4 * 16);
        #pragma unroll
        for (int m = 0; m < 4; ++m)
            #pragma unroll
            for (int n = 0; n < 4; ++n)
                acc[m][n] = __builtin_amdgcn_mfma_f32_16x16x32_bf16(af[m], bfr[n], acc[m][n], 0, 0, 0);
        __syncthreads();
    }
    #pragma unroll
    for (int m = 0; m < 4; ++m) {
        int row = m0 + wr * 64 + m * 16 + l4 * 4;
        #pragma unroll
        for (int n = 0; n < 4; ++n) {
            int col = n0 + wc * 64 + n * 16 + l15;
            float bias = b1[col];
            #pragma unroll
            for (int j = 0; j < 4; ++j)
                H[(size_t)(row + j) * NH1 + col] = __float2bfloat16(gelu_tanh(acc[m][n][j] + bias));
        }
    }
}

// ---------------- GEMM2 MFMA, all levels: per level (2048 x 1152) -> out slice ----------------

__global__ __launch_bounds__(256) void gemm2_all(
    const __hip_bfloat16* __restrict__ Hin,  // [4][3][2048][NH1]
    const __hip_bfloat16* __restrict__ Bt,   // [NH2][NH1]
    const float* __restrict__ b2,
    float* __restrict__ out) {
    __shared__ __align__(16) char smem[8192];
    char* Asm = smem;         // 64 rows x 64B
    char* Bsm = smem + 4096;
    const int lev = blockIdx.x >> 5;
    const int m0 = (blockIdx.x & 31) * 64, n0 = blockIdx.y * 64;
    const int tid = threadIdx.x;
    const int w = tid >> 6, l = tid & 63;
    const int wr = w >> 1, wc = w & 1;
    const int l15 = l & 15, l4 = l >> 4;
    f32x4 acc[2][2];
    #pragma unroll
    for (int m = 0; m < 2; ++m)
        #pragma unroll
        for (int n = 0; n < 2; ++n) acc[m][n] = (f32x4){0.f, 0.f, 0.f, 0.f};
    const char* Bg = (const char*)(Bt + (size_t)(n0 + (tid >> 2)) * NH1) + (tid & 3) * 16;
    char* AsmW = Asm + w * 1024;
    char* BsmW = Bsm + w * 1024;
    for (int p = 0; p < 3; ++p) {
        const char* Ag = (const char*)(Hin
            + (size_t)((lev * 3 + p) * 2048 + m0 + (tid >> 2)) * NH1) + (tid & 3) * 16;
        for (int jb = 0; jb < NH1 * 2; jb += 64) {
            gload16(Ag + jb, AsmW);
            gload16(Bg + jb, BsmW);
            __syncthreads();
            short8 af[2], bfr[2];
            #pragma unroll
            for (int m = 0; m < 2; ++m)
                af[m] = *(const short8*)(Asm + (wr * 32 + m * 16 + l15) * 64 + l4 * 16);
            #pragma unroll
            for (int n = 0; n < 2; ++n)
                bfr[n] = *(const short8*)(Bsm + (wc * 32 + n * 16 + l15) * 64 + l4 * 16);
            #pragma unroll
            for (int m = 0; m < 2; ++m)
                #pragma unroll
                for (int n = 0; n < 2; ++n)
                    acc[m][n] = __builtin_amdgcn_mfma_f32_16x16x32_bf16(af[m], bfr[n], acc[m][n], 0, 0, 0);
            __syncthreads();
        }
    }
    #pragma unroll
    for (int m = 0; m < 2; ++m) {
        int row = m0 + wr * 32 + m * 16 + l4 * 4;
        #pragma unroll
        for (int n = 0; n < 2; ++n) {
            int col = n0 + wc * 32 + n * 16 + l15;
            float bias3 = 3.f * b2[col];
            #pragma unroll
            for (int j = 0; j < 4; ++j)
                out[(size_t)(row + j) * 1024 + lev * NH2 + col] = acc[m][n][j] + bias3;
        }
    }
}

// ---------------- launch ----------------

extern "C" void kernel_launch(void* const* d_in, const int* in_sizes, int n_in,
                              void* d_out, int out_size, void* d_ws, size_t ws_size,
                              hipStream_t stream) {
    const float* coords      = (const float*)d_in[0];
    const float* coords_init = (const float*)d_in[1];
    const float* fp0         = (const float*)d_in[2];
    const float* w1          = (const float*)d_in[3];
    const float* b1          = (const float*)d_in[4];
    const float* w2          = (const float*)d_in[5];
    const float* b2          = (const float*)d_in[6];
    float* out = (float*)d_out;
    char* ws = (char*)d_ws;

    __hip_bfloat16* lev0 = (__hip_bfloat16*)ws;      ws += SZ_L0 * 2;
    __hip_bfloat16* lev1 = (__hip_bfloat16*)ws;      ws += SZ_L1 * 2;
    __hip_bfloat16* lev2 = (__hip_bfloat16*)ws;      ws += SZ_L2 * 2;
    __hip_bfloat16* lev3 = (__hip_bfloat16*)ws;      ws += SZ_L3 * 2;
    __hip_bfloat16* tfb  = (__hip_bfloat16*)ws;      ws += (size_t)4 * SZ_TF * 2;
    __hip_bfloat16* c4b  = (__hip_bfloat16*)ws;      ws += (size_t)24576 * LDK * 2;
    __hip_bfloat16* h_ws = (__hip_bfloat16*)ws;      ws += (size_t)24576 * NH1 * 2;
    __hip_bfloat16* w1t  = (__hip_bfloat16*)ws;      ws += (size_t)NH1 * LDK * 2;
    __hip_bfloat16* w2t  = (__hip_bfloat16*)ws;      ws += (size_t)NH2 * NH1 * 2;

    prep_w1t<<<dim3(38, 6), 256, 0, stream>>>(w1, w1t);
    prep_w2t<<<(NH2 * NH1 + 255) / 256, 256, 0, stream>>>(w2, w2t);

    cvt_cl_kernel<<<24 * 96, 256, 0, stream>>>(fp0, lev0);
    pool_cl<<<(int)((SZ_L1 / 8 + 255) / 256), 256, 0, stream>>>(lev0, lev1, 96, (int)(SZ_L1 / 8));
    pool_cl<<<(int)((SZ_L2 / 8 + 255) / 256), 256, 0, stream>>>(lev1, lev2, 48, (int)(SZ_L2 / 8));
    pool_cl<<<(int)((SZ_L3 / 8 + 255) / 256), 256, 0, stream>>>(lev2, lev3, 24, (int)(SZ_L3 / 8));

    tf_all<<<4 * 768, 256, 0, stream>>>(lev0, coords_init, tfb);
    corr_all<<<3072, 256, 0, stream>>>(lev0, coords, tfb, c4b);
    gemm1_all<<<576, 256, 0, stream>>>(c4b, w1t, b1, h_ws);
    gemm2_all<<<dim3(128, 4), 256, 0, stream>>>(h_ws, w2t, b2, out);
}

// Round 18
// 252.597 us; speedup vs baseline: 1.7206x; 1.7206x over previous
//
#include <hip/hip_runtime.h>
#include <hip/hip_bf16.h>
#include <math.h>

#define NTRK 256
#define DLAT 128
#define CDIM 7
#define CD2  49
#define CD4  2401
#define NH1  384
#define NH2  256
#define LDK  2432    // CD4 padded to multiple of 32
#define PITCHB 272   // corr LDS row pitch in bytes (136 bf16 / 68 dwords) -> 4-bank skew

// channel-last level sizes (elements)
#define SZ_L0 ((size_t)3 * 8 * 96 * 96 * 128)
#define SZ_L1 ((size_t)3 * 8 * 48 * 48 * 128)
#define SZ_L2 ((size_t)3 * 8 * 24 * 24 * 128)
#define SZ_L3 ((size_t)3 * 8 * 12 * 12 * 128)
#define SZ_TF ((size_t)3 * NTRK * DLAT * CD2)

typedef __attribute__((ext_vector_type(8))) short short8;
typedef __attribute__((ext_vector_type(4))) float f32x4;
typedef __attribute__((ext_vector_type(4))) unsigned int u32x4;

// ---------------- helpers ----------------

__device__ __forceinline__ float b2f(unsigned short u) {
    union { unsigned int i; float f; } c;
    c.i = ((unsigned int)u) << 16;
    return c.f;
}
__device__ __forceinline__ unsigned int f2b(float x) {
    __hip_bfloat16 h = __float2bfloat16(x);
    return (unsigned int)(*(unsigned short*)&h);
}

// 0.5x(1+tanh(u)) == x*sigmoid(2u), u = 0.7978845608(x + 0.044715 x^3)
__device__ __forceinline__ float gelu_tanh(float x) {
    float x2 = x * x;
    float p = x * fmaf(0.044715f, x2, 1.0f);
    float e = __expf(-1.5957691216f * p);   // e^{-2u}
    return __fdividef(x, 1.0f + e);
}

__device__ __forceinline__ int plane_a(int k) { return (k == 2) ? 1 : 0; }
__device__ __forceinline__ int plane_b(int k) { return (k == 0) ? 1 : 2; }

__device__ __forceinline__ int lev_v(int lev) { return 96 >> lev; }
__device__ __forceinline__ size_t lev_off(int lev) {
    return (lev > 0 ? SZ_L0 : 0) + (lev > 1 ? SZ_L1 : 0) + (lev > 2 ? SZ_L2 : 0);
}

// async global->LDS, 16B per lane; LDS dst must be wave-uniform base
__device__ __forceinline__ void gload16(const void* g, void* l) {
    __builtin_amdgcn_global_load_lds(
        (const __attribute__((address_space(1))) unsigned int*)g,
        (__attribute__((address_space(3))) unsigned int*)l,
        16, 0, 0);
}

// ---------------- fp32 channel-first -> bf16 channel-last transpose ----------------

__global__ __launch_bounds__(256) void cvt_cl_kernel(const float* __restrict__ in,
                                                     __hip_bfloat16* __restrict__ out) {
    __shared__ unsigned int lds[64][97];   // lds[d2][x] = bf16(2*d2) | bf16(2*d2+1)<<16
    const int b = blockIdx.x;      // (k*8+s)*96 + y
    const int y = b % 96;
    const int ks = b / 96;         // k*8+s
    const int k = ks >> 3, s = ks & 7;
    const int tid = threadIdx.x;
    for (int idx = tid; idx < 64 * 24; idx += 256) {
        int d2 = idx / 24, x4 = (idx - d2 * 24) * 4;
        const float* rlo = in + (((size_t)s * 384 + (2 * d2) * 3 + k) * 96 + y) * 96 + x4;
        const float* rhi = in + (((size_t)s * 384 + (2 * d2 + 1) * 3 + k) * 96 + y) * 96 + x4;
        float4 lo = *(const float4*)rlo;
        float4 hi = *(const float4*)rhi;
        lds[d2][x4 + 0] = f2b(lo.x) | (f2b(hi.x) << 16);
        lds[d2][x4 + 1] = f2b(lo.y) | (f2b(hi.y) << 16);
        lds[d2][x4 + 2] = f2b(lo.z) | (f2b(hi.z) << 16);
        lds[d2][x4 + 3] = f2b(lo.w) | (f2b(hi.w) << 16);
    }
    __syncthreads();
    unsigned int* orow = (unsigned int*)((unsigned short*)out + ((size_t)ks * 96 + y) * 96 * 128);
    for (int idx = tid; idx < 96 * 16; idx += 256) {
        int x = idx >> 4, q = idx & 15;
        u32x4 r;
        r[0] = lds[4 * q + 0][x];
        r[1] = lds[4 * q + 1][x];
        r[2] = lds[4 * q + 2][x];
        r[3] = lds[4 * q + 3][x];
        *(u32x4*)(orow + x * 64 + q * 4) = r;
    }
}

// ---------------- 2x2 avg pool, channel-last bf16 ----------------

__global__ __launch_bounds__(256) void pool_cl(const __hip_bfloat16* __restrict__ in,
                                               __hip_bfloat16* __restrict__ out,
                                               int vin, int total8) {
    int idx = blockIdx.x * 256 + threadIdx.x;
    if (idx >= total8) return;
    int vout = vin >> 1;
    int d8 = idx & 15;
    int t = idx >> 4;
    int x = t % vout; t /= vout;
    int y = t % vout; t /= vout;   // t = ks
    const unsigned short* base = (const unsigned short*)in
        + (((size_t)t * vin + 2 * y) * vin + 2 * x) * 128 + d8 * 8;
    short8 a = *(const short8*)(base);
    short8 bq = *(const short8*)(base + 128);
    short8 c = *(const short8*)(base + (size_t)vin * 128);
    short8 d = *(const short8*)(base + (size_t)vin * 128 + 128);
    short8 r;
    #pragma unroll
    for (int j = 0; j < 8; ++j) {
        float sum = b2f((unsigned short)a[j]) + b2f((unsigned short)bq[j])
                  + b2f((unsigned short)c[j]) + b2f((unsigned short)d[j]);
        r[j] = (short)f2b(0.25f * sum);
    }
    *(short8*)((unsigned short*)out + ((((size_t)t * vout + y) * vout + x)) * 128 + d8 * 8) = r;
}

// ---------------- track features, all levels: grid 4*768 ----------------

__global__ __launch_bounds__(256) void tf_all(const __hip_bfloat16* __restrict__ levbase,
                                              const float* __restrict__ coords_init,
                                              __hip_bfloat16* __restrict__ tfb) {
    const int bid = blockIdx.x;
    const int lev = bid / 768;
    const int r0 = bid - lev * 768;
    const int g = (r0 & 7) * 96 + (r0 >> 3);
    const int k = g >> 8;
    const int n = g & 255;
    const int v = lev_v(lev);
    const float inv_scale = 1.f / (float)(1 << lev);
    const float vm1 = (float)(v - 1);
    float cx = coords_init[n * 3 + plane_a(k)] * inv_scale;
    float cy = coords_init[n * 3 + plane_b(k)] * inv_scale;
    const unsigned short* frame = (const unsigned short*)levbase + lev_off(lev)
        + (size_t)(k * 8) * v * v * 128;
    unsigned short* dst = (unsigned short*)tfb + (size_t)lev * SZ_TF
        + ((size_t)(k * NTRK + n)) * (DLAT * CD2);
    for (int idx = threadIdx.x; idx < CD2 * 16; idx += 256) {
        int xy = idx >> 4;
        int c8 = idx & 15;
        int i = xy / CDIM, j = xy % CDIM;
        float X = fminf(fmaxf(cx + (float)(i - 3), 0.f), vm1);
        float Y = fminf(fmaxf(cy + (float)(j - 3), 0.f), vm1);
        float xf = floorf(X), yf = floorf(Y);
        int x0 = (int)xf, y0 = (int)yf;
        int x1 = min(x0 + 1, v - 1), y1 = min(y0 + 1, v - 1);
        float wx = X - xf, wy = Y - yf;
        const unsigned short* r00 = frame + ((size_t)y0 * v + x0) * 128 + c8 * 8;
        const unsigned short* r01 = frame + ((size_t)y0 * v + x1) * 128 + c8 * 8;
        const unsigned short* r10 = frame + ((size_t)y1 * v + x0) * 128 + c8 * 8;
        const unsigned short* r11 = frame + ((size_t)y1 * v + x1) * 128 + c8 * 8;
        short8 a = *(const short8*)r00, bq = *(const short8*)r01;
        short8 c = *(const short8*)r10, d = *(const short8*)r11;
        float w00 = (1.f - wy) * (1.f - wx), w01 = (1.f - wy) * wx;
        float w10 = wy * (1.f - wx), w11 = wy * wx;
        short8 r;
        #pragma unroll
        for (int e = 0; e < 8; ++e) {
            float val = b2f((unsigned short)a[e]) * w00 + b2f((unsigned short)bq[e]) * w01
                      + b2f((unsigned short)c[e]) * w10 + b2f((unsigned short)d[e]) * w11;
            r[e] = (short)f2b(val);
        }
        *(short8*)(dst + xy * 128 + c8 * 8) = r;
    }
}

// ---------------- fused patch-MFMA correlation, s-batched + s-pipelined: grid 3072 ----------------
// r16 structure (3 barriers, tfs in LDS, Cfull into patch, 35.3KB LDS / 4 blocks/CU)
// + PARTIAL bf-fragment hoist: nt=0,1 fragments live in 32 VGPRs (s-invariant),
// nt=2,3 still read from LDS -> MFMA-phase LDS reads 20 -> 12 per lane per s.
// (r17 lesson: hoisting all 16 frags spilled to scratch; ~32 VGPRs of headroom only.)
// Patch axis convention (verified r6): output (h,w) samples X=cx+(h-3), Y=cy+(w-3);
// patch pos = py*8+px (px<->x); tap for (h,w) is pos = w*8+h; wx=wxs[h], wy=wys[w].

__global__ __launch_bounds__(256) void corr_all(const __hip_bfloat16* __restrict__ levbase,
                                                const float* __restrict__ coords,
                                                const __hip_bfloat16* __restrict__ tfb,
                                                __hip_bfloat16* __restrict__ c4b) {
    __shared__ __align__(16) char patch[64 * PITCHB];  // P bf16 [pos][dd]; later Cfull fp32 [pos][xy]
    __shared__ __align__(16) char tfs[64 * PITCHB];    // tf bf16 [xy][dd]
    __shared__ float wxs[8], wys[8];
    const int bid = blockIdx.x;
    const int lk = bid >> 8;          // lev*3 + k
    const int n = bid & 255;
    const int lev = lk / 3;
    const int k = lk - lev * 3;
    const int v = lev_v(lev);
    const int vv = v * v;
    const float inv_scale = 1.f / (float)(1 << lev);
    const int tid = threadIdx.x;
    const float vm1 = (float)(v - 1);

    const int w4 = tid >> 6, l = tid & 63;
    const int l15 = l & 15, l4 = l >> 4;

    // stage tf once (s-invariant)
    const short8* tfg = (const short8*)(tfb + (size_t)lev * SZ_TF
        + ((size_t)(k * NTRK + n)) * (DLAT * CD2));
    for (int idx = tid; idx < 784; idx += 256) {
        int row = idx >> 4, c16 = idx & 15;
        *(short8*)(tfs + row * PITCHB + c16 * 16) = tfg[idx];
    }
    __syncthreads();

    // hoist nt=0,1 bf fragments to registers (8 x short8 = 32 VGPRs)
    short8 bfr01[2][4];
    #pragma unroll
    for (int nt = 0; nt < 2; ++nt)
        #pragma unroll
        for (int ks = 0; ks < 4; ++ks)
            bfr01[nt][ks] = *(const short8*)(tfs + (16 * nt + l15) * PITCHB + ks * 64 + l4 * 16);

    // per-thread interp decode, computed once: hw = hwb + 5*it, xy fixed
    const int hwb = tid / 49;           // 0..5 (valid <245)
    const int xy  = tid - hwb * 49;
    const bool act = tid < 245;

    const unsigned short* fbase = (const unsigned short*)levbase + lev_off(lev)
        + (size_t)(k * 8) * vv * 128;

    // per-lane staging geometry: pos = posb + 16q, fixed c8
    const int c8 = tid & 15;
    const int posb = tid >> 4;

    float cxc, cyc; int fxc, fyc;
    short8 pre[4];

    auto CALC = [&](int s) {
        const int sn = s * 256 + n;
        cxc = coords[sn * 3 + plane_a(k)] * inv_scale;
        cyc = coords[sn * 3 + plane_b(k)] * inv_scale;
        fxc = (int)floorf(cxc);
        fyc = (int)floorf(cyc);
    };
    auto PREF = [&](int s) {
        const unsigned short* frame = fbase + (size_t)s * vv * 128;
        #pragma unroll
        for (int q = 0; q < 4; ++q) {
            int pos = posb + 16 * q;
            int px = pos & 7, py = pos >> 3;
            int gx = min(max(fxc + px - 3, 0), v - 1);
            int gy = min(max(fyc + py - 3, 0), v - 1);
            pre[q] = *(const short8*)(frame + ((size_t)gy * v + gx) * 128 + c8 * 8);
        }
    };

    CALC(0); PREF(0);
    for (int s = 0; s < 8; ++s) {
        const float cx = cxc, cy = cyc;
        const int fx = fxc, fy = fyc;
        // block-uniform interpolation weights (0 at clamped taps)
        if (tid < 7) {
            float X = fminf(fmaxf(cx + (float)(tid - 3), 0.f), vm1);
            int g = min(max(fx + tid - 3, 0), v - 1);
            wxs[tid] = X - (float)g;
            float Y = fminf(fmaxf(cy + (float)(tid - 3), 0.f), vm1);
            int gy_ = min(max(fy + tid - 3, 0), v - 1);
            wys[tid] = Y - (float)gy_;
        }
        // commit prefetched patch to LDS
        #pragma unroll
        for (int q = 0; q < 4; ++q)
            *(short8*)(patch + (posb + 16 * q) * PITCHB + c8 * 16) = pre[q];
        __syncthreads();

        f32x4 acc[4];
        #pragma unroll
        for (int nt = 0; nt < 4; ++nt) acc[nt] = (f32x4){0.f, 0.f, 0.f, 0.f};
        #pragma unroll
        for (int ks = 0; ks < 4; ++ks) {
            short8 af = *(const short8*)(patch + (16 * w4 + l15) * PITCHB + ks * 64 + l4 * 16);
            acc[0] = __builtin_amdgcn_mfma_f32_16x16x32_bf16(af, bfr01[0][ks], acc[0], 0, 0, 0);
            acc[1] = __builtin_amdgcn_mfma_f32_16x16x32_bf16(af, bfr01[1][ks], acc[1], 0, 0, 0);
            #pragma unroll
            for (int nt = 2; nt < 4; ++nt) {
                short8 bf = *(const short8*)(tfs + (16 * nt + l15) * PITCHB + ks * 64 + l4 * 16);
                acc[nt] = __builtin_amdgcn_mfma_f32_16x16x32_bf16(af, bf, acc[nt], 0, 0, 0);
            }
        }
        // issue next-s global loads; they complete under Cfull+interp phases
        if (s < 7) { CALC(s + 1); PREF(s + 1); }
        __syncthreads();  // all patch reads done before overwrite

        // write Cfull fp32 [pos][xy] into the patch region (64 x 272B >= 64 x 256B)
        {
            const int row0 = 16 * w4 + l4 * 4;
            #pragma unroll
            for (int nt = 0; nt < 4; ++nt) {
                int col = nt * 16 + l15;
                #pragma unroll
                for (int j = 0; j < 4; ++j)
                    *(float*)(patch + (row0 + j) * PITCHB + col * 4) = acc[nt][j];
            }
        }
        __syncthreads();

        // division-free 4-tap interpolation; output (h,w): tap pos = w*8+h
        unsigned short* crow = (unsigned short*)c4b + ((size_t)lk * 2048 + s * 256 + n) * LDK;
        if (act) {
            int h = 0, w = hwb;
            unsigned short* op = crow + tid;   // hwb*49 + xy == tid
            const char* colbase = patch + xy * 4;
            #pragma unroll
            for (int it = 0; it < 10; ++it) {
                if (h < 7) {
                    float wxv = wxs[h], wyv = wys[w];
                    const char* tap = colbase + (w * 8 + h) * PITCHB;
                    float p00 = *(const float*)(tap);
                    float p01 = *(const float*)(tap + PITCHB);        // x+1
                    float p10 = *(const float*)(tap + 8 * PITCHB);    // y+1
                    float p11 = *(const float*)(tap + 9 * PITCHB);
                    float a  = fmaf(wxv, p01 - p00, p00);
                    float bq = fmaf(wxv, p11 - p10, p10);
                    *op = (unsigned short)f2b(fmaf(wyv, bq - a, a));
                }
                w += 5; if (w >= 7) { w -= 7; h += 1; }
                op += 245;
            }
        }
        if (tid < LDK - CD4) crow[CD4 + tid] = 0;   // bf16 zero pad
        __syncthreads();  // interp reads done before next-s staging
    }
}

// ---------------- weight prep: coalesced LDS-tile transpose + bf16 ----------------

__global__ __launch_bounds__(256) void prep_w1t(const float* __restrict__ w1,
                                                __hip_bfloat16* __restrict__ w1t) {
    __shared__ float t[64][65];
    const int kk0 = blockIdx.x * 64, n0 = blockIdx.y * 64;
    const int tid = threadIdx.x;
    for (int idx = tid; idx < 4096; idx += 256) {
        int r = idx >> 6, c = idx & 63;        // r: kk offset, c: n offset
        int kk = kk0 + r;
        t[r][c] = (kk < CD4) ? w1[(size_t)kk * NH1 + n0 + c] : 0.f;
    }
    __syncthreads();
    for (int idx = tid; idx < 4096; idx += 256) {
        int r = idx >> 6, c = idx & 63;        // r: n offset, c: kk offset
        w1t[(size_t)(n0 + r) * LDK + kk0 + c] = __float2bfloat16(t[c][r]);
    }
}

__global__ __launch_bounds__(256) void prep_w2t(const float* __restrict__ w2,
                                                __hip_bfloat16* __restrict__ w2t) {
    int idx = blockIdx.x * 256 + threadIdx.x;  // n*NH1 + j
    if (idx >= NH2 * NH1) return;
    int n = idx / NH1, j = idx - n * NH1;
    w2t[idx] = __float2bfloat16(w2[(size_t)j * NH2 + n]);
}

// ---------------- GEMM1 MFMA, all levels: (24576 x LDK) @ w1t^T -> gelu -> H bf16 ----------------
// BM=128 BN=128 BK=32, 4 waves (2x2), wave tile 64x64 = 4x4 frags.
// 1D grid 576; XCD-aware decode: g=id/24, m=g*8+id%8, y=(id%24)/8.

__global__ __launch_bounds__(256) void gemm1_all(
    const __hip_bfloat16* __restrict__ A,    // [24576][LDK]
    const __hip_bfloat16* __restrict__ Bt,   // [NH1][LDK]
    const float* __restrict__ b1,
    __hip_bfloat16* __restrict__ H) {        // [24576][NH1]
    __shared__ __align__(16) char smem[16384];
    char* Asm = smem;          // 128 rows x 64B
    char* Bsm = smem + 8192;   // 128 rows x 64B
    const int id = blockIdx.x;
    const int gq = id / 24, rq = id - gq * 24;
    const int m0 = (gq * 8 + (rq & 7)) * 128;
    const int n0 = (rq >> 3) * 128;
    const int tid = threadIdx.x;
    const int w = tid >> 6, l = tid & 63;
    const int wr = w >> 1, wc = w & 1;
    const int l15 = l & 15, l4 = l >> 4;
    f32x4 acc[4][4];
    #pragma unroll
    for (int m = 0; m < 4; ++m)
        #pragma unroll
        for (int n = 0; n < 4; ++n) acc[m][n] = (f32x4){0.f, 0.f, 0.f, 0.f};
    const char* Ag = (const char*)(A + (size_t)(m0 + (tid >> 2)) * LDK) + (tid & 3) * 16;
    const char* Bg = (const char*)(Bt + (size_t)(n0 + (tid >> 2)) * LDK) + (tid & 3) * 16;
    char* AsmW = Asm + w * 1024;
    char* BsmW = Bsm + w * 1024;
    for (int kb = 0; kb < LDK * 2; kb += 64) {  // byte offset along K
        gload16(Ag + kb, AsmW);
        gload16(Ag + (size_t)64 * LDK * 2 + kb, AsmW + 4096);
        gload16(Bg + kb, BsmW);
        gload16(Bg + (size_t)64 * LDK * 2 + kb, BsmW + 4096);
        __syncthreads();
        short8 af[4], bfr[4];
        #pragma unroll
        for (int m = 0; m < 4; ++m)
            af[m] = *(const short8*)(Asm + (wr * 64 + m * 16 + l15) * 64 + l4 * 16);
        #pragma unroll
        for (int n = 0; n < 4; ++n)
            bfr[n] = *(const short8*)(Bsm + (wc * 64 + n * 16 + l15) * 64 + l4 * 16);
        #pragma unroll
        for (int m = 0; m < 4; ++m)
            #pragma unroll
            for (int n = 0; n < 4; ++n)
                acc[m][n] = __builtin_amdgcn_mfma_f32_16x16x32_bf16(af[m], bfr[n], acc[m][n], 0, 0, 0);
        __syncthreads();
    }
    #pragma unroll
    for (int m = 0; m < 4; ++m) {
        int row = m0 + wr * 64 + m * 16 + l4 * 4;
        #pragma unroll
        for (int n = 0; n < 4; ++n) {
            int col = n0 + wc * 64 + n * 16 + l15;
            float bias = b1[col];
            #pragma unroll
            for (int j = 0; j < 4; ++j)
                H[(size_t)(row + j) * NH1 + col] = __float2bfloat16(gelu_tanh(acc[m][n][j] + bias));
        }
    }
}

// ---------------- GEMM2 MFMA, all levels: per level (2048 x 1152) -> out slice ----------------

__global__ __launch_bounds__(256) void gemm2_all(
    const __hip_bfloat16* __restrict__ Hin,  // [4][3][2048][NH1]
    const __hip_bfloat16* __restrict__ Bt,   // [NH2][NH1]
    const float* __restrict__ b2,
    float* __restrict__ out) {
    __shared__ __align__(16) char smem[8192];
    char* Asm = smem;         // 64 rows x 64B
    char* Bsm = smem + 4096;
    const int lev = blockIdx.x >> 5;
    const int m0 = (blockIdx.x & 31) * 64, n0 = blockIdx.y * 64;
    const int tid = threadIdx.x;
    const int w = tid >> 6, l = tid & 63;
    const int wr = w >> 1, wc = w & 1;
    const int l15 = l & 15, l4 = l >> 4;
    f32x4 acc[2][2];
    #pragma unroll
    for (int m = 0; m < 2; ++m)
        #pragma unroll
        for (int n = 0; n < 2; ++n) acc[m][n] = (f32x4){0.f, 0.f, 0.f, 0.f};
    const char* Bg = (const char*)(Bt + (size_t)(n0 + (tid >> 2)) * NH1) + (tid & 3) * 16;
    char* AsmW = Asm + w * 1024;
    char* BsmW = Bsm + w * 1024;
    for (int p = 0; p < 3; ++p) {
        const char* Ag = (const char*)(Hin
            + (size_t)((lev * 3 + p) * 2048 + m0 + (tid >> 2)) * NH1) + (tid & 3) * 16;
        for (int jb = 0; jb < NH1 * 2; jb += 64) {
            gload16(Ag + jb, AsmW);
            gload16(Bg + jb, BsmW);
            __syncthreads();
            short8 af[2], bfr[2];
            #pragma unroll
            for (int m = 0; m < 2; ++m)
                af[m] = *(const short8*)(Asm + (wr * 32 + m * 16 + l15) * 64 + l4 * 16);
            #pragma unroll
            for (int n = 0; n < 2; ++n)
                bfr[n] = *(const short8*)(Bsm + (wc * 32 + n * 16 + l15) * 64 + l4 * 16);
            #pragma unroll
            for (int m = 0; m < 2; ++m)
                #pragma unroll
                for (int n = 0; n < 2; ++n)
                    acc[m][n] = __builtin_amdgcn_mfma_f32_16x16x32_bf16(af[m], bfr[n], acc[m][n], 0, 0, 0);
            __syncthreads();
        }
    }
    #pragma unroll
    for (int m = 0; m < 2; ++m) {
        int row = m0 + wr * 32 + m * 16 + l4 * 4;
        #pragma unroll
        for (int n = 0; n < 2; ++n) {
            int col = n0 + wc * 32 + n * 16 + l15;
            float bias3 = 3.f * b2[col];
            #pragma unroll
            for (int j = 0; j < 4; ++j)
                out[(size_t)(row + j) * 1024 + lev * NH2 + col] = acc[m][n][j] + bias3;
        }
    }
}

// ---------------- launch ----------------

extern "C" void kernel_launch(void* const* d_in, const int* in_sizes, int n_in,
                              void* d_out, int out_size, void* d_ws, size_t ws_size,
                              hipStream_t stream) {
    const float* coords      = (const float*)d_in[0];
    const float* coords_init = (const float*)d_in[1];
    const float* fp0         = (const float*)d_in[2];
    const float* w1          = (const float*)d_in[3];
    const float* b1          = (const float*)d_in[4];
    const float* w2          = (const float*)d_in[5];
    const float* b2          = (const float*)d_in[6];
    float* out = (float*)d_out;
    char* ws = (char*)d_ws;

    __hip_bfloat16* lev0 = (__hip_bfloat16*)ws;      ws += SZ_L0 * 2;
    __hip_bfloat16* lev1 = (__hip_bfloat16*)ws;      ws += SZ_L1 * 2;
    __hip_bfloat16* lev2 = (__hip_bfloat16*)ws;      ws += SZ_L2 * 2;
    __hip_bfloat16* lev3 = (__hip_bfloat16*)ws;      ws += SZ_L3 * 2;
    __hip_bfloat16* tfb  = (__hip_bfloat16*)ws;      ws += (size_t)4 * SZ_TF * 2;
    __hip_bfloat16* c4b  = (__hip_bfloat16*)ws;      ws += (size_t)24576 * LDK * 2;
    __hip_bfloat16* h_ws = (__hip_bfloat16*)ws;      ws += (size_t)24576 * NH1 * 2;
    __hip_bfloat16* w1t  = (__hip_bfloat16*)ws;      ws += (size_t)NH1 * LDK * 2;
    __hip_bfloat16* w2t  = (__hip_bfloat16*)ws;      ws += (size_t)NH2 * NH1 * 2;

    prep_w1t<<<dim3(38, 6), 256, 0, stream>>>(w1, w1t);
    prep_w2t<<<(NH2 * NH1 + 255) / 256, 256, 0, stream>>>(w2, w2t);

    cvt_cl_kernel<<<24 * 96, 256, 0, stream>>>(fp0, lev0);
    pool_cl<<<(int)((SZ_L1 / 8 + 255) / 256), 256, 0, stream>>>(lev0, lev1, 96, (int)(SZ_L1 / 8));
    pool_cl<<<(int)((SZ_L2 / 8 + 255) / 256), 256, 0, stream>>>(lev1, lev2, 48, (int)(SZ_L2 / 8));
    pool_cl<<<(int)((SZ_L3 / 8 + 255) / 256), 256, 0, stream>>>(lev2, lev3, 24, (int)(SZ_L3 / 8));

    tf_all<<<4 * 768, 256, 0, stream>>>(lev0, coords_init, tfb);
    corr_all<<<3072, 256, 0, stream>>>(lev0, coords, tfb, c4b);
    gemm1_all<<<576, 256, 0, stream>>>(c4b, w1t, b1, h_ws);
    gemm2_all<<<dim3(128, 4), 256, 0, stream>>>(h_ws, w2t, b2, out);
}

// Round 19
// 240.746 us; speedup vs baseline: 1.8053x; 1.0492x over previous
//
#include <hip/hip_runtime.h>
#include <hip/hip_bf16.h>
#include <math.h>

#define NTRK 256
#define DLAT 128
#define CDIM 7
#define CD2  49
#define CD4  2401
#define NH1  384
#define NH2  256
#define LDK  2432    // CD4 padded to multiple of 32
#define PITCHB 272   // corr LDS row pitch in bytes (136 bf16 / 68 dwords) -> 4-bank skew

// channel-last level sizes (elements)
#define SZ_L0 ((size_t)3 * 8 * 96 * 96 * 128)
#define SZ_L1 ((size_t)3 * 8 * 48 * 48 * 128)
#define SZ_L2 ((size_t)3 * 8 * 24 * 24 * 128)
#define SZ_L3 ((size_t)3 * 8 * 12 * 12 * 128)

typedef __attribute__((ext_vector_type(8))) short short8;
typedef __attribute__((ext_vector_type(4))) float f32x4;
typedef __attribute__((ext_vector_type(4))) unsigned int u32x4;

// ---------------- helpers ----------------

__device__ __forceinline__ float b2f(unsigned short u) {
    union { unsigned int i; float f; } c;
    c.i = ((unsigned int)u) << 16;
    return c.f;
}
__device__ __forceinline__ unsigned int f2b(float x) {
    __hip_bfloat16 h = __float2bfloat16(x);
    return (unsigned int)(*(unsigned short*)&h);
}

// 0.5x(1+tanh(u)) == x*sigmoid(2u), u = 0.7978845608(x + 0.044715 x^3)
__device__ __forceinline__ float gelu_tanh(float x) {
    float x2 = x * x;
    float p = x * fmaf(0.044715f, x2, 1.0f);
    float e = __expf(-1.5957691216f * p);   // e^{-2u}
    return __fdividef(x, 1.0f + e);
}

__device__ __forceinline__ int plane_a(int k) { return (k == 2) ? 1 : 0; }
__device__ __forceinline__ int plane_b(int k) { return (k == 0) ? 1 : 2; }

__device__ __forceinline__ int lev_v(int lev) { return 96 >> lev; }
__device__ __forceinline__ size_t lev_off(int lev) {
    return (lev > 0 ? SZ_L0 : 0) + (lev > 1 ? SZ_L1 : 0) + (lev > 2 ? SZ_L2 : 0);
}

// async global->LDS, 16B per lane; LDS dst must be wave-uniform base
__device__ __forceinline__ void gload16(const void* g, void* l) {
    __builtin_amdgcn_global_load_lds(
        (const __attribute__((address_space(1))) unsigned int*)g,
        (__attribute__((address_space(3))) unsigned int*)l,
        16, 0, 0);
}

// ---------------- fp32 channel-first -> bf16 channel-last transpose ----------------

__global__ __launch_bounds__(256) void cvt_cl_kernel(const float* __restrict__ in,
                                                     __hip_bfloat16* __restrict__ out) {
    __shared__ unsigned int lds[64][97];   // lds[d2][x] = bf16(2*d2) | bf16(2*d2+1)<<16
    const int b = blockIdx.x;      // (k*8+s)*96 + y
    const int y = b % 96;
    const int ks = b / 96;         // k*8+s
    const int k = ks >> 3, s = ks & 7;
    const int tid = threadIdx.x;
    for (int idx = tid; idx < 64 * 24; idx += 256) {
        int d2 = idx / 24, x4 = (idx - d2 * 24) * 4;
        const float* rlo = in + (((size_t)s * 384 + (2 * d2) * 3 + k) * 96 + y) * 96 + x4;
        const float* rhi = in + (((size_t)s * 384 + (2 * d2 + 1) * 3 + k) * 96 + y) * 96 + x4;
        float4 lo = *(const float4*)rlo;
        float4 hi = *(const float4*)rhi;
        lds[d2][x4 + 0] = f2b(lo.x) | (f2b(hi.x) << 16);
        lds[d2][x4 + 1] = f2b(lo.y) | (f2b(hi.y) << 16);
        lds[d2][x4 + 2] = f2b(lo.z) | (f2b(hi.z) << 16);
        lds[d2][x4 + 3] = f2b(lo.w) | (f2b(hi.w) << 16);
    }
    __syncthreads();
    unsigned int* orow = (unsigned int*)((unsigned short*)out + ((size_t)ks * 96 + y) * 96 * 128);
    for (int idx = tid; idx < 96 * 16; idx += 256) {
        int x = idx >> 4, q = idx & 15;
        u32x4 r;
        r[0] = lds[4 * q + 0][x];
        r[1] = lds[4 * q + 1][x];
        r[2] = lds[4 * q + 2][x];
        r[3] = lds[4 * q + 3][x];
        *(u32x4*)(orow + x * 64 + q * 4) = r;
    }
}

// ---------------- 2x2 avg pool, channel-last bf16 ----------------

__global__ __launch_bounds__(256) void pool_cl(const __hip_bfloat16* __restrict__ in,
                                               __hip_bfloat16* __restrict__ out,
                                               int vin, int total8) {
    int idx = blockIdx.x * 256 + threadIdx.x;
    if (idx >= total8) return;
    int vout = vin >> 1;
    int d8 = idx & 15;
    int t = idx >> 4;
    int x = t % vout; t /= vout;
    int y = t % vout; t /= vout;   // t = ks
    const unsigned short* base = (const unsigned short*)in
        + (((size_t)t * vin + 2 * y) * vin + 2 * x) * 128 + d8 * 8;
    short8 a = *(const short8*)(base);
    short8 bq = *(const short8*)(base + 128);
    short8 c = *(const short8*)(base + (size_t)vin * 128);
    short8 d = *(const short8*)(base + (size_t)vin * 128 + 128);
    short8 r;
    #pragma unroll
    for (int j = 0; j < 8; ++j) {
        float sum = b2f((unsigned short)a[j]) + b2f((unsigned short)bq[j])
                  + b2f((unsigned short)c[j]) + b2f((unsigned short)d[j]);
        r[j] = (short)f2b(0.25f * sum);
    }
    *(short8*)((unsigned short*)out + ((((size_t)t * vout + y) * vout + x)) * 128 + d8 * 8) = r;
}

// ---------------- fused tf-sampling + patch-MFMA correlation: grid 3072 ----------------
// r18 structure (3 barriers, tfs in LDS, Cfull into patch, 35.3KB LDS / 4 blocks/CU,
// partial bf hoist nt=0,1) + tf_all FUSED into the prologue: tf is sampled bilinearly
// from frame 0 (channel-last short8 loads) directly into tfs -- eliminates the tf_all
// dispatch and the 77MB tfb round-trip. Numerics identical (same fp32->bf16 rounding).
// Patch axis convention (verified r6): output (h,w) samples X=cx+(h-3), Y=cy+(w-3);
// patch pos = py*8+px (px<->x); tap for (h,w) is pos = w*8+h; wx=wxs[h], wy=wys[w].
// tf row xy = i*7+j sampled at X=tcx+(i-3), Y=tcy+(j-3) (tf_all convention).

__global__ __launch_bounds__(256) void corr_all(const __hip_bfloat16* __restrict__ levbase,
                                                const float* __restrict__ coords,
                                                const float* __restrict__ coords_init,
                                                __hip_bfloat16* __restrict__ c4b) {
    __shared__ __align__(16) char patch[64 * PITCHB];  // P bf16 [pos][dd]; later Cfull fp32 [pos][xy]
    __shared__ __align__(16) char tfs[64 * PITCHB];    // tf bf16 [xy][dd]
    __shared__ float wxs[8], wys[8];
    const int bid = blockIdx.x;
    const int lk = bid >> 8;          // lev*3 + k
    const int n = bid & 255;
    const int lev = lk / 3;
    const int k = lk - lev * 3;
    const int v = lev_v(lev);
    const int vv = v * v;
    const float inv_scale = 1.f / (float)(1 << lev);
    const int tid = threadIdx.x;
    const float vm1 = (float)(v - 1);

    const int w4 = tid >> 6, l = tid & 63;
    const int l15 = l & 15, l4 = l >> 4;

    const unsigned short* fbase = (const unsigned short*)levbase + lev_off(lev)
        + (size_t)(k * 8) * vv * 128;

    // ---- fused tf sampling: 49 x 128 bilinear from frame 0 into tfs ----
    {
        const float tcx = coords_init[n * 3 + plane_a(k)] * inv_scale;
        const float tcy = coords_init[n * 3 + plane_b(k)] * inv_scale;
        for (int idx = tid; idx < 784; idx += 256) {
            int xy = idx >> 4;
            int cc = idx & 15;
            int i = xy / CDIM, j = xy - i * CDIM;
            float X = fminf(fmaxf(tcx + (float)(i - 3), 0.f), vm1);
            float Y = fminf(fmaxf(tcy + (float)(j - 3), 0.f), vm1);
            float xf = floorf(X), yf = floorf(Y);
            int x0 = (int)xf, y0 = (int)yf;
            int x1 = min(x0 + 1, v - 1), y1 = min(y0 + 1, v - 1);
            float wx = X - xf, wy = Y - yf;
            const unsigned short* r00 = fbase + ((size_t)y0 * v + x0) * 128 + cc * 8;
            const unsigned short* r01 = fbase + ((size_t)y0 * v + x1) * 128 + cc * 8;
            const unsigned short* r10 = fbase + ((size_t)y1 * v + x0) * 128 + cc * 8;
            const unsigned short* r11 = fbase + ((size_t)y1 * v + x1) * 128 + cc * 8;
            short8 a = *(const short8*)r00, bq = *(const short8*)r01;
            short8 c = *(const short8*)r10, d = *(const short8*)r11;
            float w00 = (1.f - wy) * (1.f - wx), w01 = (1.f - wy) * wx;
            float w10 = wy * (1.f - wx), w11 = wy * wx;
            short8 r;
            #pragma unroll
            for (int e = 0; e < 8; ++e) {
                float val = b2f((unsigned short)a[e]) * w00 + b2f((unsigned short)bq[e]) * w01
                          + b2f((unsigned short)c[e]) * w10 + b2f((unsigned short)d[e]) * w11;
                r[e] = (short)f2b(val);
            }
            *(short8*)(tfs + xy * PITCHB + cc * 16) = r;
        }
    }
    __syncthreads();

    // hoist nt=0,1 bf fragments to registers (8 x short8 = 32 VGPRs)
    short8 bfr01[2][4];
    #pragma unroll
    for (int nt = 0; nt < 2; ++nt)
        #pragma unroll
        for (int ks = 0; ks < 4; ++ks)
            bfr01[nt][ks] = *(const short8*)(tfs + (16 * nt + l15) * PITCHB + ks * 64 + l4 * 16);

    // per-thread interp decode, computed once: hw = hwb + 5*it, xy fixed
    const int hwb = tid / 49;           // 0..5 (valid <245)
    const int xy  = tid - hwb * 49;
    const bool act = tid < 245;

    // per-lane staging geometry: pos = posb + 16q, fixed c8
    const int c8 = tid & 15;
    const int posb = tid >> 4;

    float cxc, cyc; int fxc, fyc;
    short8 pre[4];

    auto CALC = [&](int s) {
        const int sn = s * 256 + n;
        cxc = coords[sn * 3 + plane_a(k)] * inv_scale;
        cyc = coords[sn * 3 + plane_b(k)] * inv_scale;
        fxc = (int)floorf(cxc);
        fyc = (int)floorf(cyc);
    };
    auto PREF = [&](int s) {
        const unsigned short* frame = fbase + (size_t)s * vv * 128;
        #pragma unroll
        for (int q = 0; q < 4; ++q) {
            int pos = posb + 16 * q;
            int px = pos & 7, py = pos >> 3;
            int gx = min(max(fxc + px - 3, 0), v - 1);
            int gy = min(max(fyc + py - 3, 0), v - 1);
            pre[q] = *(const short8*)(frame + ((size_t)gy * v + gx) * 128 + c8 * 8);
        }
    };

    CALC(0); PREF(0);
    for (int s = 0; s < 8; ++s) {
        const float cx = cxc, cy = cyc;
        const int fx = fxc, fy = fyc;
        // block-uniform interpolation weights (0 at clamped taps)
        if (tid < 7) {
            float X = fminf(fmaxf(cx + (float)(tid - 3), 0.f), vm1);
            int g = min(max(fx + tid - 3, 0), v - 1);
            wxs[tid] = X - (float)g;
            float Y = fminf(fmaxf(cy + (float)(tid - 3), 0.f), vm1);
            int gy_ = min(max(fy + tid - 3, 0), v - 1);
            wys[tid] = Y - (float)gy_;
        }
        // commit prefetched patch to LDS
        #pragma unroll
        for (int q = 0; q < 4; ++q)
            *(short8*)(patch + (posb + 16 * q) * PITCHB + c8 * 16) = pre[q];
        __syncthreads();

        f32x4 acc[4];
        #pragma unroll
        for (int nt = 0; nt < 4; ++nt) acc[nt] = (f32x4){0.f, 0.f, 0.f, 0.f};
        #pragma unroll
        for (int ks = 0; ks < 4; ++ks) {
            short8 af = *(const short8*)(patch + (16 * w4 + l15) * PITCHB + ks * 64 + l4 * 16);
            acc[0] = __builtin_amdgcn_mfma_f32_16x16x32_bf16(af, bfr01[0][ks], acc[0], 0, 0, 0);
            acc[1] = __builtin_amdgcn_mfma_f32_16x16x32_bf16(af, bfr01[1][ks], acc[1], 0, 0, 0);
            #pragma unroll
            for (int nt = 2; nt < 4; ++nt) {
                short8 bf = *(const short8*)(tfs + (16 * nt + l15) * PITCHB + ks * 64 + l4 * 16);
                acc[nt] = __builtin_amdgcn_mfma_f32_16x16x32_bf16(af, bf, acc[nt], 0, 0, 0);
            }
        }
        // issue next-s global loads; they complete under Cfull+interp phases
        if (s < 7) { CALC(s + 1); PREF(s + 1); }
        __syncthreads();  // all patch reads done before overwrite

        // write Cfull fp32 [pos][xy] into the patch region (64 x 272B >= 64 x 256B)
        {
            const int row0 = 16 * w4 + l4 * 4;
            #pragma unroll
            for (int nt = 0; nt < 4; ++nt) {
                int col = nt * 16 + l15;
                #pragma unroll
                for (int j = 0; j < 4; ++j)
                    *(float*)(patch + (row0 + j) * PITCHB + col * 4) = acc[nt][j];
            }
        }
        __syncthreads();

        // division-free 4-tap interpolation; output (h,w): tap pos = w*8+h
        unsigned short* crow = (unsigned short*)c4b + ((size_t)lk * 2048 + s * 256 + n) * LDK;
        if (act) {
            int h = 0, w = hwb;
            unsigned short* op = crow + tid;   // hwb*49 + xy == tid
            const char* colbase = patch + xy * 4;
            #pragma unroll
            for (int it = 0; it < 10; ++it) {
                if (h < 7) {
                    float wxv = wxs[h], wyv = wys[w];
                    const char* tap = colbase + (w * 8 + h) * PITCHB;
                    float p00 = *(const float*)(tap);
                    float p01 = *(const float*)(tap + PITCHB);        // x+1
                    float p10 = *(const float*)(tap + 8 * PITCHB);    // y+1
                    float p11 = *(const float*)(tap + 9 * PITCHB);
                    float a  = fmaf(wxv, p01 - p00, p00);
                    float bq = fmaf(wxv, p11 - p10, p10);
                    *op = (unsigned short)f2b(fmaf(wyv, bq - a, a));
                }
                w += 5; if (w >= 7) { w -= 7; h += 1; }
                op += 245;
            }
        }
        if (tid < LDK - CD4) crow[CD4 + tid] = 0;   // bf16 zero pad
        __syncthreads();  // interp reads done before next-s staging
    }
}

// ---------------- weight prep: coalesced LDS-tile transpose + bf16 ----------------

__global__ __launch_bounds__(256) void prep_w1t(const float* __restrict__ w1,
                                                __hip_bfloat16* __restrict__ w1t) {
    __shared__ float t[64][65];
    const int kk0 = blockIdx.x * 64, n0 = blockIdx.y * 64;
    const int tid = threadIdx.x;
    for (int idx = tid; idx < 4096; idx += 256) {
        int r = idx >> 6, c = idx & 63;        // r: kk offset, c: n offset
        int kk = kk0 + r;
        t[r][c] = (kk < CD4) ? w1[(size_t)kk * NH1 + n0 + c] : 0.f;
    }
    __syncthreads();
    for (int idx = tid; idx < 4096; idx += 256) {
        int r = idx >> 6, c = idx & 63;        // r: n offset, c: kk offset
        w1t[(size_t)(n0 + r) * LDK + kk0 + c] = __float2bfloat16(t[c][r]);
    }
}

__global__ __launch_bounds__(256) void prep_w2t(const float* __restrict__ w2,
                                                __hip_bfloat16* __restrict__ w2t) {
    int idx = blockIdx.x * 256 + threadIdx.x;  // n*NH1 + j
    if (idx >= NH2 * NH1) return;
    int n = idx / NH1, j = idx - n * NH1;
    w2t[idx] = __float2bfloat16(w2[(size_t)j * NH2 + n]);
}

// ---------------- GEMM1 MFMA, all levels: (24576 x LDK) @ w1t^T -> gelu -> H bf16 ----------------
// BM=128 BN=128 BK=32, 4 waves (2x2), wave tile 64x64 = 4x4 frags.
// 1D grid 576; XCD-aware decode: g=id/24, m=g*8+id%8, y=(id%24)/8.

__global__ __launch_bounds__(256) void gemm1_all(
    const __hip_bfloat16* __restrict__ A,    // [24576][LDK]
    const __hip_bfloat16* __restrict__ Bt,   // [NH1][LDK]
    const float* __restrict__ b1,
    __hip_bfloat16* __restrict__ H) {        // [24576][NH1]
    __shared__ __align__(16) char smem[16384];
    char* Asm = smem;          // 128 rows x 64B
    char* Bsm = smem + 8192;   // 128 rows x 64B
    const int id = blockIdx.x;
    const int gq = id / 24, rq = id - gq * 24;
    const int m0 = (gq * 8 + (rq & 7)) * 128;
    const int n0 = (rq >> 3) * 128;
    const int tid = threadIdx.x;
    const int w = tid >> 6, l = tid & 63;
    const int wr = w >> 1, wc = w & 1;
    const int l15 = l & 15, l4 = l >> 4;
    f32x4 acc[4][4];
    #pragma unroll
    for (int m = 0; m < 4; ++m)
        #pragma unroll
        for (int n = 0; n < 4; ++n) acc[m][n] = (f32x4){0.f, 0.f, 0.f, 0.f};
    const char* Ag = (const char*)(A + (size_t)(m0 + (tid >> 2)) * LDK) + (tid & 3) * 16;
    const char* Bg = (const char*)(Bt + (size_t)(n0 + (tid >> 2)) * LDK) + (tid & 3) * 16;
    char* AsmW = Asm + w * 1024;
    char* BsmW = Bsm + w * 1024;
    for (int kb = 0; kb < LDK * 2; kb += 64) {  // byte offset along K
        gload16(Ag + kb, AsmW);
        gload16(Ag + (size_t)64 * LDK * 2 + kb, AsmW + 4096);
        gload16(Bg + kb, BsmW);
        gload16(Bg + (size_t)64 * LDK * 2 + kb, BsmW + 4096);
        __syncthreads();
        short8 af[4], bfr[4];
        #pragma unroll
        for (int m = 0; m < 4; ++m)
            af[m] = *(const short8*)(Asm + (wr * 64 + m * 16 + l15) * 64 + l4 * 16);
        #pragma unroll
        for (int n = 0; n < 4; ++n)
            bfr[n] = *(const short8*)(Bsm + (wc * 64 + n * 16 + l15) * 64 + l4 * 16);
        #pragma unroll
        for (int m = 0; m < 4; ++m)
            #pragma unroll
            for (int n = 0; n < 4; ++n)
                acc[m][n] = __builtin_amdgcn_mfma_f32_16x16x32_bf16(af[m], bfr[n], acc[m][n], 0, 0, 0);
        __syncthreads();
    }
    #pragma unroll
    for (int m = 0; m < 4; ++m) {
        int row = m0 + wr * 64 + m * 16 + l4 * 4;
        #pragma unroll
        for (int n = 0; n < 4; ++n) {
            int col = n0 + wc * 64 + n * 16 + l15;
            float bias = b1[col];
            #pragma unroll
            for (int j = 0; j < 4; ++j)
                H[(size_t)(row + j) * NH1 + col] = __float2bfloat16(gelu_tanh(acc[m][n][j] + bias));
        }
    }
}

// ---------------- GEMM2 MFMA, all levels: per level (2048 x 1152) -> out slice ----------------

__global__ __launch_bounds__(256) void gemm2_all(
    const __hip_bfloat16* __restrict__ Hin,  // [4][3][2048][NH1]
    const __hip_bfloat16* __restrict__ Bt,   // [NH2][NH1]
    const float* __restrict__ b2,
    float* __restrict__ out) {
    __shared__ __align__(16) char smem[8192];
    char* Asm = smem;         // 64 rows x 64B
    char* Bsm = smem + 4096;
    const int lev = blockIdx.x >> 5;
    const int m0 = (blockIdx.x & 31) * 64, n0 = blockIdx.y * 64;
    const int tid = threadIdx.x;
    const int w = tid >> 6, l = tid & 63;
    const int wr = w >> 1, wc = w & 1;
    const int l15 = l & 15, l4 = l >> 4;
    f32x4 acc[2][2];
    #pragma unroll
    for (int m = 0; m < 2; ++m)
        #pragma unroll
        for (int n = 0; n < 2; ++n) acc[m][n] = (f32x4){0.f, 0.f, 0.f, 0.f};
    const char* Bg = (const char*)(Bt + (size_t)(n0 + (tid >> 2)) * NH1) + (tid & 3) * 16;
    char* AsmW = Asm + w * 1024;
    char* BsmW = Bsm + w * 1024;
    for (int p = 0; p < 3; ++p) {
        const char* Ag = (const char*)(Hin
            + (size_t)((lev * 3 + p) * 2048 + m0 + (tid >> 2)) * NH1) + (tid & 3) * 16;
        for (int jb = 0; jb < NH1 * 2; jb += 64) {
            gload16(Ag + jb, AsmW);
            gload16(Bg + jb, BsmW);
            __syncthreads();
            short8 af[2], bfr[2];
            #pragma unroll
            for (int m = 0; m < 2; ++m)
                af[m] = *(const short8*)(Asm + (wr * 32 + m * 16 + l15) * 64 + l4 * 16);
            #pragma unroll
            for (int n = 0; n < 2; ++n)
                bfr[n] = *(const short8*)(Bsm + (wc * 32 + n * 16 + l15) * 64 + l4 * 16);
            #pragma unroll
            for (int m = 0; m < 2; ++m)
                #pragma unroll
                for (int n = 0; n < 2; ++n)
                    acc[m][n] = __builtin_amdgcn_mfma_f32_16x16x32_bf16(af[m], bfr[n], acc[m][n], 0, 0, 0);
            __syncthreads();
        }
    }
    #pragma unroll
    for (int m = 0; m < 2; ++m) {
        int row = m0 + wr * 32 + m * 16 + l4 * 4;
        #pragma unroll
        for (int n = 0; n < 2; ++n) {
            int col = n0 + wc * 32 + n * 16 + l15;
            float bias3 = 3.f * b2[col];
            #pragma unroll
            for (int j = 0; j < 4; ++j)
                out[(size_t)(row + j) * 1024 + lev * NH2 + col] = acc[m][n][j] + bias3;
        }
    }
}

// ---------------- launch ----------------

extern "C" void kernel_launch(void* const* d_in, const int* in_sizes, int n_in,
                              void* d_out, int out_size, void* d_ws, size_t ws_size,
                              hipStream_t stream) {
    const float* coords      = (const float*)d_in[0];
    const float* coords_init = (const float*)d_in[1];
    const float* fp0         = (const float*)d_in[2];
    const float* w1          = (const float*)d_in[3];
    const float* b1          = (const float*)d_in[4];
    const float* w2          = (const float*)d_in[5];
    const float* b2          = (const float*)d_in[6];
    float* out = (float*)d_out;
    char* ws = (char*)d_ws;

    __hip_bfloat16* lev0 = (__hip_bfloat16*)ws;      ws += SZ_L0 * 2;
    __hip_bfloat16* lev1 = (__hip_bfloat16*)ws;      ws += SZ_L1 * 2;
    __hip_bfloat16* lev2 = (__hip_bfloat16*)ws;      ws += SZ_L2 * 2;
    __hip_bfloat16* lev3 = (__hip_bfloat16*)ws;      ws += SZ_L3 * 2;
    __hip_bfloat16* c4b  = (__hip_bfloat16*)ws;      ws += (size_t)24576 * LDK * 2;
    __hip_bfloat16* h_ws = (__hip_bfloat16*)ws;      ws += (size_t)24576 * NH1 * 2;
    __hip_bfloat16* w1t  = (__hip_bfloat16*)ws;      ws += (size_t)NH1 * LDK * 2;
    __hip_bfloat16* w2t  = (__hip_bfloat16*)ws;      ws += (size_t)NH2 * NH1 * 2;

    prep_w1t<<<dim3(38, 6), 256, 0, stream>>>(w1, w1t);
    prep_w2t<<<(NH2 * NH1 + 255) / 256, 256, 0, stream>>>(w2, w2t);

    cvt_cl_kernel<<<24 * 96, 256, 0, stream>>>(fp0, lev0);
    pool_cl<<<(int)((SZ_L1 / 8 + 255) / 256), 256, 0, stream>>>(lev0, lev1, 96, (int)(SZ_L1 / 8));
    pool_cl<<<(int)((SZ_L2 / 8 + 255) / 256), 256, 0, stream>>>(lev1, lev2, 48, (int)(SZ_L2 / 8));
    pool_cl<<<(int)((SZ_L3 / 8 + 255) / 256), 256, 0, stream>>>(lev2, lev3, 24, (int)(SZ_L3 / 8));

    corr_all<<<3072, 256, 0, stream>>>(lev0, coords, coords_init, c4b);
    gemm1_all<<<576, 256, 0, stream>>>(c4b, w1t, b1, h_ws);
    gemm2_all<<<dim3(128, 4), 256, 0, stream>>>(h_ws, w2t, b2, out);
}

// Round 20
// 239.701 us; speedup vs baseline: 1.8132x; 1.0044x over previous
//
#include <hip/hip_runtime.h>
#include <hip/hip_bf16.h>
#include <math.h>

#define NTRK 256
#define DLAT 128
#define CDIM 7
#define CD2  49
#define CD4  2401
#define NH1  384
#define NH2  256
#define LDK  2432    // CD4 padded to multiple of 32
#define PITCHB 272   // corr LDS row pitch in bytes (136 bf16 / 68 dwords) -> 4-bank skew

// channel-last level sizes (elements)
#define SZ_L0 ((size_t)3 * 8 * 96 * 96 * 128)
#define SZ_L1 ((size_t)3 * 8 * 48 * 48 * 128)
#define SZ_L2 ((size_t)3 * 8 * 24 * 24 * 128)
#define SZ_L3 ((size_t)3 * 8 * 12 * 12 * 128)

typedef __attribute__((ext_vector_type(8))) short short8;
typedef __attribute__((ext_vector_type(4))) float f32x4;
typedef __attribute__((ext_vector_type(4))) unsigned int u32x4;

// ---------------- helpers ----------------

__device__ __forceinline__ float b2f(unsigned short u) {
    union { unsigned int i; float f; } c;
    c.i = ((unsigned int)u) << 16;
    return c.f;
}
__device__ __forceinline__ unsigned int f2b(float x) {
    __hip_bfloat16 h = __float2bfloat16(x);
    return (unsigned int)(*(unsigned short*)&h);
}

// 0.5x(1+tanh(u)) == x*sigmoid(2u), u = 0.7978845608(x + 0.044715 x^3)
__device__ __forceinline__ float gelu_tanh(float x) {
    float x2 = x * x;
    float p = x * fmaf(0.044715f, x2, 1.0f);
    float e = __expf(-1.5957691216f * p);   // e^{-2u}
    return __fdividef(x, 1.0f + e);
}

__device__ __forceinline__ int plane_a(int k) { return (k == 2) ? 1 : 0; }
__device__ __forceinline__ int plane_b(int k) { return (k == 0) ? 1 : 2; }

__device__ __forceinline__ int lev_v(int lev) { return 96 >> lev; }
__device__ __forceinline__ size_t lev_off(int lev) {
    return (lev > 0 ? SZ_L0 : 0) + (lev > 1 ? SZ_L1 : 0) + (lev > 2 ? SZ_L2 : 0);
}

// async global->LDS, 16B per lane; LDS dst must be wave-uniform base
__device__ __forceinline__ void gload16(const void* g, void* l) {
    __builtin_amdgcn_global_load_lds(
        (const __attribute__((address_space(1))) unsigned int*)g,
        (__attribute__((address_space(3))) unsigned int*)l,
        16, 0, 0);
}

// ---------------- fp32 channel-first -> bf16 channel-last transpose ----------------

__global__ __launch_bounds__(256) void cvt_cl_kernel(const float* __restrict__ in,
                                                     __hip_bfloat16* __restrict__ out) {
    __shared__ unsigned int lds[64][97];   // lds[d2][x] = bf16(2*d2) | bf16(2*d2+1)<<16
    const int b = blockIdx.x;      // (k*8+s)*96 + y
    const int y = b % 96;
    const int ks = b / 96;         // k*8+s
    const int k = ks >> 3, s = ks & 7;
    const int tid = threadIdx.x;
    for (int idx = tid; idx < 64 * 24; idx += 256) {
        int d2 = idx / 24, x4 = (idx - d2 * 24) * 4;
        const float* rlo = in + (((size_t)s * 384 + (2 * d2) * 3 + k) * 96 + y) * 96 + x4;
        const float* rhi = in + (((size_t)s * 384 + (2 * d2 + 1) * 3 + k) * 96 + y) * 96 + x4;
        float4 lo = *(const float4*)rlo;
        float4 hi = *(const float4*)rhi;
        lds[d2][x4 + 0] = f2b(lo.x) | (f2b(hi.x) << 16);
        lds[d2][x4 + 1] = f2b(lo.y) | (f2b(hi.y) << 16);
        lds[d2][x4 + 2] = f2b(lo.z) | (f2b(hi.z) << 16);
        lds[d2][x4 + 3] = f2b(lo.w) | (f2b(hi.w) << 16);
    }
    __syncthreads();
    unsigned int* orow = (unsigned int*)((unsigned short*)out + ((size_t)ks * 96 + y) * 96 * 128);
    for (int idx = tid; idx < 96 * 16; idx += 256) {
        int x = idx >> 4, q = idx & 15;
        u32x4 r;
        r[0] = lds[4 * q + 0][x];
        r[1] = lds[4 * q + 1][x];
        r[2] = lds[4 * q + 2][x];
        r[3] = lds[4 * q + 3][x];
        *(u32x4*)(orow + x * 64 + q * 4) = r;
    }
}

// ---------------- 2x2 avg pool, channel-last bf16 ----------------

__global__ __launch_bounds__(256) void pool_cl(const __hip_bfloat16* __restrict__ in,
                                               __hip_bfloat16* __restrict__ out,
                                               int vin, int total8) {
    int idx = blockIdx.x * 256 + threadIdx.x;
    if (idx >= total8) return;
    int vout = vin >> 1;
    int d8 = idx & 15;
    int t = idx >> 4;
    int x = t % vout; t /= vout;
    int y = t % vout; t /= vout;   // t = ks
    const unsigned short* base = (const unsigned short*)in
        + (((size_t)t * vin + 2 * y) * vin + 2 * x) * 128 + d8 * 8;
    short8 a = *(const short8*)(base);
    short8 bq = *(const short8*)(base + 128);
    short8 c = *(const short8*)(base + (size_t)vin * 128);
    short8 d = *(const short8*)(base + (size_t)vin * 128 + 128);
    short8 r;
    #pragma unroll
    for (int j = 0; j < 8; ++j) {
        float sum = b2f((unsigned short)a[j]) + b2f((unsigned short)bq[j])
                  + b2f((unsigned short)c[j]) + b2f((unsigned short)d[j]);
        r[j] = (short)f2b(0.25f * sum);
    }
    *(short8*)((unsigned short*)out + ((((size_t)t * vout + y) * vout + x)) * 128 + d8 * 8) = r;
}

// ---------------- fused tf-sampling + patch-MFMA correlation: grid 3072 ----------------
// r19 structure + tfs shrunk to its 49 REAL rows (13.3KB): total LDS 30.8KB -> 5 blocks/CU
// (was 4). Rows 49..63 of the B operand are N-padding whose products land in Cfull
// cols 49..63 that interp never reads -> the nt=3 fragment row is clamped to 48
// (bit-exact for the live col l15=0; garbage-but-unread otherwise; always in-bounds).
// Patch axis convention (verified r6): output (h,w) samples X=cx+(h-3), Y=cy+(w-3);
// patch pos = py*8+px (px<->x); tap for (h,w) is pos = w*8+h; wx=wxs[h], wy=wys[w].
// tf row xy = i*7+j sampled at X=tcx+(i-3), Y=tcy+(j-3).

__global__ __launch_bounds__(256) void corr_all(const __hip_bfloat16* __restrict__ levbase,
                                                const float* __restrict__ coords,
                                                const float* __restrict__ coords_init,
                                                __hip_bfloat16* __restrict__ c4b) {
    __shared__ __align__(16) char patch[64 * PITCHB];  // P bf16 [pos][dd]; later Cfull fp32 [pos][xy]
    __shared__ __align__(16) char tfs[49 * PITCHB];    // tf bf16 [xy][dd], 49 real rows only
    __shared__ float wxs[8], wys[8];
    const int bid = blockIdx.x;
    const int lk = bid >> 8;          // lev*3 + k
    const int n = bid & 255;
    const int lev = lk / 3;
    const int k = lk - lev * 3;
    const int v = lev_v(lev);
    const int vv = v * v;
    const float inv_scale = 1.f / (float)(1 << lev);
    const int tid = threadIdx.x;
    const float vm1 = (float)(v - 1);

    const int w4 = tid >> 6, l = tid & 63;
    const int l15 = l & 15, l4 = l >> 4;

    const unsigned short* fbase = (const unsigned short*)levbase + lev_off(lev)
        + (size_t)(k * 8) * vv * 128;

    // ---- fused tf sampling: 49 x 128 bilinear from frame 0 into tfs ----
    {
        const float tcx = coords_init[n * 3 + plane_a(k)] * inv_scale;
        const float tcy = coords_init[n * 3 + plane_b(k)] * inv_scale;
        for (int idx = tid; idx < 784; idx += 256) {
            int xy = idx >> 4;
            int cc = idx & 15;
            int i = xy / CDIM, j = xy - i * CDIM;
            float X = fminf(fmaxf(tcx + (float)(i - 3), 0.f), vm1);
            float Y = fminf(fmaxf(tcy + (float)(j - 3), 0.f), vm1);
            float xf = floorf(X), yf = floorf(Y);
            int x0 = (int)xf, y0 = (int)yf;
            int x1 = min(x0 + 1, v - 1), y1 = min(y0 + 1, v - 1);
            float wx = X - xf, wy = Y - yf;
            const unsigned short* r00 = fbase + ((size_t)y0 * v + x0) * 128 + cc * 8;
            const unsigned short* r01 = fbase + ((size_t)y0 * v + x1) * 128 + cc * 8;
            const unsigned short* r10 = fbase + ((size_t)y1 * v + x0) * 128 + cc * 8;
            const unsigned short* r11 = fbase + ((size_t)y1 * v + x1) * 128 + cc * 8;
            short8 a = *(const short8*)r00, bq = *(const short8*)r01;
            short8 c = *(const short8*)r10, d = *(const short8*)r11;
            float w00 = (1.f - wy) * (1.f - wx), w01 = (1.f - wy) * wx;
            float w10 = wy * (1.f - wx), w11 = wy * wx;
            short8 r;
            #pragma unroll
            for (int e = 0; e < 8; ++e) {
                float val = b2f((unsigned short)a[e]) * w00 + b2f((unsigned short)bq[e]) * w01
                          + b2f((unsigned short)c[e]) * w10 + b2f((unsigned short)d[e]) * w11;
                r[e] = (short)f2b(val);
            }
            *(short8*)(tfs + xy * PITCHB + cc * 16) = r;
        }
    }
    __syncthreads();

    // hoist nt=0,1 bf fragments to registers (8 x short8 = 32 VGPRs)
    short8 bfr01[2][4];
    #pragma unroll
    for (int nt = 0; nt < 2; ++nt)
        #pragma unroll
        for (int ks = 0; ks < 4; ++ks)
            bfr01[nt][ks] = *(const short8*)(tfs + (16 * nt + l15) * PITCHB + ks * 64 + l4 * 16);

    // per-thread interp decode, computed once: hw = hwb + 5*it, xy fixed
    const int hwb = tid / 49;           // 0..5 (valid <245)
    const int xy  = tid - hwb * 49;
    const bool act = tid < 245;

    // per-lane staging geometry: pos = posb + 16q, fixed c8
    const int c8 = tid & 15;
    const int posb = tid >> 4;

    float cxc, cyc; int fxc, fyc;
    short8 pre[4];

    auto CALC = [&](int s) {
        const int sn = s * 256 + n;
        cxc = coords[sn * 3 + plane_a(k)] * inv_scale;
        cyc = coords[sn * 3 + plane_b(k)] * inv_scale;
        fxc = (int)floorf(cxc);
        fyc = (int)floorf(cyc);
    };
    auto PREF = [&](int s) {
        const unsigned short* frame = fbase + (size_t)s * vv * 128;
        #pragma unroll
        for (int q = 0; q < 4; ++q) {
            int pos = posb + 16 * q;
            int px = pos & 7, py = pos >> 3;
            int gx = min(max(fxc + px - 3, 0), v - 1);
            int gy = min(max(fyc + py - 3, 0), v - 1);
            pre[q] = *(const short8*)(frame + ((size_t)gy * v + gx) * 128 + c8 * 8);
        }
    };

    CALC(0); PREF(0);
    for (int s = 0; s < 8; ++s) {
        const float cx = cxc, cy = cyc;
        const int fx = fxc, fy = fyc;
        // block-uniform interpolation weights (0 at clamped taps)
        if (tid < 7) {
            float X = fminf(fmaxf(cx + (float)(tid - 3), 0.f), vm1);
            int g = min(max(fx + tid - 3, 0), v - 1);
            wxs[tid] = X - (float)g;
            float Y = fminf(fmaxf(cy + (float)(tid - 3), 0.f), vm1);
            int gy_ = min(max(fy + tid - 3, 0), v - 1);
            wys[tid] = Y - (float)gy_;
        }
        // commit prefetched patch to LDS
        #pragma unroll
        for (int q = 0; q < 4; ++q)
            *(short8*)(patch + (posb + 16 * q) * PITCHB + c8 * 16) = pre[q];
        __syncthreads();

        f32x4 acc[4];
        #pragma unroll
        for (int nt = 0; nt < 4; ++nt) acc[nt] = (f32x4){0.f, 0.f, 0.f, 0.f};
        #pragma unroll
        for (int ks = 0; ks < 4; ++ks) {
            short8 af = *(const short8*)(patch + (16 * w4 + l15) * PITCHB + ks * 64 + l4 * 16);
            acc[0] = __builtin_amdgcn_mfma_f32_16x16x32_bf16(af, bfr01[0][ks], acc[0], 0, 0, 0);
            acc[1] = __builtin_amdgcn_mfma_f32_16x16x32_bf16(af, bfr01[1][ks], acc[1], 0, 0, 0);
            #pragma unroll
            for (int nt = 2; nt < 4; ++nt) {
                int rrow = min(16 * nt + l15, 48);   // rows >48 are dead-N padding
                short8 bf = *(const short8*)(tfs + rrow * PITCHB + ks * 64 + l4 * 16);
                acc[nt] = __builtin_amdgcn_mfma_f32_16x16x32_bf16(af, bf, acc[nt], 0, 0, 0);
            }
        }
        // issue next-s global loads; they complete under Cfull+interp phases
        if (s < 7) { CALC(s + 1); PREF(s + 1); }
        __syncthreads();  // all patch reads done before overwrite

        // write Cfull fp32 [pos][xy] into the patch region (64 x 272B >= 64 x 256B)
        {
            const int row0 = 16 * w4 + l4 * 4;
            #pragma unroll
            for (int nt = 0; nt < 4; ++nt) {
                int col = nt * 16 + l15;
                #pragma unroll
                for (int j = 0; j < 4; ++j)
                    *(float*)(patch + (row0 + j) * PITCHB + col * 4) = acc[nt][j];
            }
        }
        __syncthreads();

        // division-free 4-tap interpolation; output (h,w): tap pos = w*8+h
        unsigned short* crow = (unsigned short*)c4b + ((size_t)lk * 2048 + s * 256 + n) * LDK;
        if (act) {
            int h = 0, w = hwb;
            unsigned short* op = crow + tid;   // hwb*49 + xy == tid
            const char* colbase = patch + xy * 4;
            #pragma unroll
            for (int it = 0; it < 10; ++it) {
                if (h < 7) {
                    float wxv = wxs[h], wyv = wys[w];
                    const char* tap = colbase + (w * 8 + h) * PITCHB;
                    float p00 = *(const float*)(tap);
                    float p01 = *(const float*)(tap + PITCHB);        // x+1
                    float p10 = *(const float*)(tap + 8 * PITCHB);    // y+1
                    float p11 = *(const float*)(tap + 9 * PITCHB);
                    float a  = fmaf(wxv, p01 - p00, p00);
                    float bq = fmaf(wxv, p11 - p10, p10);
                    *op = (unsigned short)f2b(fmaf(wyv, bq - a, a));
                }
                w += 5; if (w >= 7) { w -= 7; h += 1; }
                op += 245;
            }
        }
        if (tid < LDK - CD4) crow[CD4 + tid] = 0;   // bf16 zero pad
        __syncthreads();  // interp reads done before next-s staging
    }
}

// ---------------- weight prep: coalesced LDS-tile transpose + bf16 ----------------

__global__ __launch_bounds__(256) void prep_w1t(const float* __restrict__ w1,
                                                __hip_bfloat16* __restrict__ w1t) {
    __shared__ float t[64][65];
    const int kk0 = blockIdx.x * 64, n0 = blockIdx.y * 64;
    const int tid = threadIdx.x;
    for (int idx = tid; idx < 4096; idx += 256) {
        int r = idx >> 6, c = idx & 63;        // r: kk offset, c: n offset
        int kk = kk0 + r;
        t[r][c] = (kk < CD4) ? w1[(size_t)kk * NH1 + n0 + c] : 0.f;
    }
    __syncthreads();
    for (int idx = tid; idx < 4096; idx += 256) {
        int r = idx >> 6, c = idx & 63;        // r: n offset, c: kk offset
        w1t[(size_t)(n0 + r) * LDK + kk0 + c] = __float2bfloat16(t[c][r]);
    }
}

__global__ __launch_bounds__(256) void prep_w2t(const float* __restrict__ w2,
                                                __hip_bfloat16* __restrict__ w2t) {
    int idx = blockIdx.x * 256 + threadIdx.x;  // n*NH1 + j
    if (idx >= NH2 * NH1) return;
    int n = idx / NH1, j = idx - n * NH1;
    w2t[idx] = __float2bfloat16(w2[(size_t)j * NH2 + n]);
}

// ---------------- GEMM1 MFMA, all levels: (24576 x LDK) @ w1t^T -> gelu -> H bf16 ----------------
// BM=128 BN=128 BK=32, 4 waves (2x2), wave tile 64x64 = 4x4 frags.
// 1D grid 576; XCD-aware decode: g=id/24, m=g*8+id%8, y=(id%24)/8.

__global__ __launch_bounds__(256) void gemm1_all(
    const __hip_bfloat16* __restrict__ A,    // [24576][LDK]
    const __hip_bfloat16* __restrict__ Bt,   // [NH1][LDK]
    const float* __restrict__ b1,
    __hip_bfloat16* __restrict__ H) {        // [24576][NH1]
    __shared__ __align__(16) char smem[16384];
    char* Asm = smem;          // 128 rows x 64B
    char* Bsm = smem + 8192;   // 128 rows x 64B
    const int id = blockIdx.x;
    const int gq = id / 24, rq = id - gq * 24;
    const int m0 = (gq * 8 + (rq & 7)) * 128;
    const int n0 = (rq >> 3) * 128;
    const int tid = threadIdx.x;
    const int w = tid >> 6, l = tid & 63;
    const int wr = w >> 1, wc = w & 1;
    const int l15 = l & 15, l4 = l >> 4;
    f32x4 acc[4][4];
    #pragma unroll
    for (int m = 0; m < 4; ++m)
        #pragma unroll
        for (int n = 0; n < 4; ++n) acc[m][n] = (f32x4){0.f, 0.f, 0.f, 0.f};
    const char* Ag = (const char*)(A + (size_t)(m0 + (tid >> 2)) * LDK) + (tid & 3) * 16;
    const char* Bg = (const char*)(Bt + (size_t)(n0 + (tid >> 2)) * LDK) + (tid & 3) * 16;
    char* AsmW = Asm + w * 1024;
    char* BsmW = Bsm + w * 1024;
    for (int kb = 0; kb < LDK * 2; kb += 64) {  // byte offset along K
        gload16(Ag + kb, AsmW);
        gload16(Ag + (size_t)64 * LDK * 2 + kb, AsmW + 4096);
        gload16(Bg + kb, BsmW);
        gload16(Bg + (size_t)64 * LDK * 2 + kb, BsmW + 4096);
        __syncthreads();
        short8 af[4], bfr[4];
        #pragma unroll
        for (int m = 0; m < 4; ++m)
            af[m] = *(const short8*)(Asm + (wr * 64 + m * 16 + l15) * 64 + l4 * 16);
        #pragma unroll
        for (int n = 0; n < 4; ++n)
            bfr[n] = *(const short8*)(Bsm + (wc * 64 + n * 16 + l15) * 64 + l4 * 16);
        #pragma unroll
        for (int m = 0; m < 4; ++m)
            #pragma unroll
            for (int n = 0; n < 4; ++n)
                acc[m][n] = __builtin_amdgcn_mfma_f32_16x16x32_bf16(af[m], bfr[n], acc[m][n], 0, 0, 0);
        __syncthreads();
    }
    #pragma unroll
    for (int m = 0; m < 4; ++m) {
        int row = m0 + wr * 64 + m * 16 + l4 * 4;
        #pragma unroll
        for (int n = 0; n < 4; ++n) {
            int col = n0 + wc * 64 + n * 16 + l15;
            float bias = b1[col];
            #pragma unroll
            for (int j = 0; j < 4; ++j)
                H[(size_t)(row + j) * NH1 + col] = __float2bfloat16(gelu_tanh(acc[m][n][j] + bias));
        }
    }
}

// ---------------- GEMM2 MFMA, all levels: per level (2048 x 1152) -> out slice ----------------

__global__ __launch_bounds__(256) void gemm2_all(
    const __hip_bfloat16* __restrict__ Hin,  // [4][3][2048][NH1]
    const __hip_bfloat16* __restrict__ Bt,   // [NH2][NH1]
    const float* __restrict__ b2,
    float* __restrict__ out) {
    __shared__ __align__(16) char smem[8192];
    char* Asm = smem;         // 64 rows x 64B
    char* Bsm = smem + 4096;
    const int lev = blockIdx.x >> 5;
    const int m0 = (blockIdx.x & 31) * 64, n0 = blockIdx.y * 64;
    const int tid = threadIdx.x;
    const int w = tid >> 6, l = tid & 63;
    const int wr = w >> 1, wc = w & 1;
    const int l15 = l & 15, l4 = l >> 4;
    f32x4 acc[2][2];
    #pragma unroll
    for (int m = 0; m < 2; ++m)
        #pragma unroll
        for (int n = 0; n < 2; ++n) acc[m][n] = (f32x4){0.f, 0.f, 0.f, 0.f};
    const char* Bg = (const char*)(Bt + (size_t)(n0 + (tid >> 2)) * NH1) + (tid & 3) * 16;
    char* AsmW = Asm + w * 1024;
    char* BsmW = Bsm + w * 1024;
    for (int p = 0; p < 3; ++p) {
        const char* Ag = (const char*)(Hin
            + (size_t)((lev * 3 + p) * 2048 + m0 + (tid >> 2)) * NH1) + (tid & 3) * 16;
        for (int jb = 0; jb < NH1 * 2; jb += 64) {
            gload16(Ag + jb, AsmW);
            gload16(Bg + jb, BsmW);
            __syncthreads();
            short8 af[2], bfr[2];
            #pragma unroll
            for (int m = 0; m < 2; ++m)
                af[m] = *(const short8*)(Asm + (wr * 32 + m * 16 + l15) * 64 + l4 * 16);
            #pragma unroll
            for (int n = 0; n < 2; ++n)
                bfr[n] = *(const short8*)(Bsm + (wc * 32 + n * 16 + l15) * 64 + l4 * 16);
            #pragma unroll
            for (int m = 0; m < 2; ++m)
                #pragma unroll
                for (int n = 0; n < 2; ++n)
                    acc[m][n] = __builtin_amdgcn_mfma_f32_16x16x32_bf16(af[m], bfr[n], acc[m][n], 0, 0, 0);
            __syncthreads();
        }
    }
    #pragma unroll
    for (int m = 0; m < 2; ++m) {
        int row = m0 + wr * 32 + m * 16 + l4 * 4;
        #pragma unroll
        for (int n = 0; n < 2; ++n) {
            int col = n0 + wc * 32 + n * 16 + l15;
            float bias3 = 3.f * b2[col];
            #pragma unroll
            for (int j = 0; j < 4; ++j)
                out[(size_t)(row + j) * 1024 + lev * NH2 + col] = acc[m][n][j] + bias3;
        }
    }
}

// ---------------- launch ----------------

extern "C" void kernel_launch(void* const* d_in, const int* in_sizes, int n_in,
                              void* d_out, int out_size, void* d_ws, size_t ws_size,
                              hipStream_t stream) {
    const float* coords      = (const float*)d_in[0];
    const float* coords_init = (const float*)d_in[1];
    const float* fp0         = (const float*)d_in[2];
    const float* w1          = (const float*)d_in[3];
    const float* b1          = (const float*)d_in[4];
    const float* w2          = (const float*)d_in[5];
    const float* b2          = (const float*)d_in[6];
    float* out = (float*)d_out;
    char* ws = (char*)d_ws;

    __hip_bfloat16* lev0 = (__hip_bfloat16*)ws;      ws += SZ_L0 * 2;
    __hip_bfloat16* lev1 = (__hip_bfloat16*)ws;      ws += SZ_L1 * 2;
    __hip_bfloat16* lev2 = (__hip_bfloat16*)ws;      ws += SZ_L2 * 2;
    __hip_bfloat16* lev3 = (__hip_bfloat16*)ws;      ws += SZ_L3 * 2;
    __hip_bfloat16* c4b  = (__hip_bfloat16*)ws;      ws += (size_t)24576 * LDK * 2;
    __hip_bfloat16* h_ws = (__hip_bfloat16*)ws;      ws += (size_t)24576 * NH1 * 2;
    __hip_bfloat16* w1t  = (__hip_bfloat16*)ws;      ws += (size_t)NH1 * LDK * 2;
    __hip_bfloat16* w2t  = (__hip_bfloat16*)ws;      ws += (size_t)NH2 * NH1 * 2;

    prep_w1t<<<dim3(38, 6), 256, 0, stream>>>(w1, w1t);
    prep_w2t<<<(NH2 * NH1 + 255) / 256, 256, 0, stream>>>(w2, w2t);

    cvt_cl_kernel<<<24 * 96, 256, 0, stream>>>(fp0, lev0);
    pool_cl<<<(int)((SZ_L1 / 8 + 255) / 256), 256, 0, stream>>>(lev0, lev1, 96, (int)(SZ_L1 / 8));
    pool_cl<<<(int)((SZ_L2 / 8 + 255) / 256), 256, 0, stream>>>(lev1, lev2, 48, (int)(SZ_L2 / 8));
    pool_cl<<<(int)((SZ_L3 / 8 + 255) / 256), 256, 0, stream>>>(lev2, lev3, 24, (int)(SZ_L3 / 8));

    corr_all<<<3072, 256, 0, stream>>>(lev0, coords, coords_init, c4b);
    gemm1_all<<<576, 256, 0, stream>>>(c4b, w1t, b1, h_ws);
    gemm2_all<<<dim3(128, 4), 256, 0, stream>>>(h_ws, w2t, b2, out);
}